// Round 3
// baseline (516.114 us; speedup 1.0000x reference)
//
#include <hip/hip_runtime.h>
#include <hip/hip_bf16.h>
#include <stdint.h>

typedef __bf16 bf16;
typedef __bf16 bf16x8 __attribute__((ext_vector_type(8)));
typedef __bf16 bf16x4 __attribute__((ext_vector_type(4)));
typedef float f32x4 __attribute__((ext_vector_type(4)));

// Tile: BM=128 (4 waves x 32 rows), BN=64, BK=64.
// A: direct global->VGPR fragments. B: global_load_lds, XOR-swizzled source,
// double-buffered (2 x 64x64 bf16 = 16 KB), one barrier per K-tile.

__device__ __forceinline__ void gload_lds16(const bf16* g, bf16* l) {
    __builtin_amdgcn_global_load_lds(
        (const __attribute__((address_space(1))) void*)g,
        (__attribute__((address_space(3))) void*)l, 16, 0, 0);
}

// Stage 64x64 bf16 B-tile. Linear LDS dest (chunk c at byte c*16); global source
// column-chunk pre-swizzled by slot^(row&7) so a swizzled ds_read sees row-major.
__device__ __forceinline__ void stageB(const bf16* __restrict__ g, int ldb,
                                       bf16* l, int t) {
#pragma unroll
    for (int i = 0; i < 2; ++i) {
        int c = (i << 8) + t;            // 0..511
        int row = c >> 3, slot = c & 7;
        gload_lds16(g + (size_t)row * ldb + ((slot ^ (row & 7)) << 3), l + c * 8);
    }
}

// One GEMM phase: C[128x64] += A[128 x nkt*64] * B^T-ish (B row d, K contiguous).
template <int NKT>
__device__ __forceinline__ void phase(const bf16* __restrict__ Ag, int lda,
                                      const bf16* __restrict__ Bg, int ldb,
                                      bf16* Bs, f32x4 acc[2][4], int t) {
    const int lane = t & 63, wv = t >> 6;
    const int arow = wv * 32 + (lane & 15);
    const int acol = (lane >> 4) << 3;   // element offset within 64-K tile

    bf16x8 aC[2][2], aN[2][2];
#pragma unroll
    for (int mi = 0; mi < 2; ++mi)
#pragma unroll
        for (int kk = 0; kk < 2; ++kk)
            aC[mi][kk] = *(const bf16x8*)&Ag[(size_t)(arow + mi * 16) * lda +
                                             kk * 32 + acol];
    stageB(Bg, ldb, Bs, t);
    __syncthreads();

#pragma unroll
    for (int kt = 0; kt < NKT; ++kt) {
        const bf16* cur = Bs + (kt & 1) * 4096;
        bf16* nxt = Bs + ((kt + 1) & 1) * 4096;
        if (kt + 1 < NKT) {
            stageB(Bg + (kt + 1) * 64, ldb, nxt, t);
#pragma unroll
            for (int mi = 0; mi < 2; ++mi)
#pragma unroll
                for (int kk = 0; kk < 2; ++kk)
                    aN[mi][kk] = *(const bf16x8*)&Ag[(size_t)(arow + mi * 16) * lda +
                                                     (kt + 1) * 64 + kk * 32 + acol];
        }
        // swizzled B fragment reads (2-way max bank aliasing)
        bf16x8 b[4][2];
#pragma unroll
        for (int ni = 0; ni < 4; ++ni) {
            int rB = ni * 16 + (lane & 15);
#pragma unroll
            for (int kk = 0; kk < 2; ++kk) {
                int kc = kk * 4 + (lane >> 4);
                b[ni][kk] = *(const bf16x8*)&cur[rB * 64 + ((kc ^ (rB & 7)) << 3)];
            }
        }
#pragma unroll
        for (int kk = 0; kk < 2; ++kk)
#pragma unroll
            for (int mi = 0; mi < 2; ++mi)
#pragma unroll
                for (int ni = 0; ni < 4; ++ni)
                    acc[mi][ni] = __builtin_amdgcn_mfma_f32_16x16x32_bf16(
                        aC[mi][kk], b[ni][kk], acc[mi][ni], 0, 0, 0);
        if (kt + 1 < NKT) {
#pragma unroll
            for (int mi = 0; mi < 2; ++mi)
#pragma unroll
                for (int kk = 0; kk < 2; ++kk) aC[mi][kk] = aN[mi][kk];
        }
        __syncthreads();   // drains stage(kt+1) + A(kt+1); releases cur for reuse
    }
}

// ---------- prep kernels ----------
__global__ void prep_alpha(const float* __restrict__ a, float* __restrict__ out) {
    int i = blockIdx.x * blockDim.x + threadIdx.x;
    if (i < 1024) out[i] = 0.5f / (1.0f + __expf(-a[i]));
}

__global__ void prep_adj(const float* __restrict__ adj, const float* __restrict__ ahs,
                         bf16* __restrict__ adjb) {
    int i = blockIdx.x * blockDim.x + threadIdx.x;  // float4 index
    int row = i >> 8;
    float s = ahs[row];
    float4 v = ((const float4*)adj)[i];
    bf16x4 o = {(bf16)(s * v.x), (bf16)(s * v.y), (bf16)(s * v.z), (bf16)(s * v.w)};
    ((bf16x4*)adjb)[i] = o;
}

__global__ void cast_f32_bf16x4(const float* __restrict__ src, bf16* __restrict__ dst,
                                int n4) {
    int i = blockIdx.x * blockDim.x + threadIdx.x;
    if (i < n4) {
        float4 v = ((const float4*)src)[i];
        bf16x4 o = {(bf16)v.x, (bf16)v.y, (bf16)v.z, (bf16)v.w};
        ((bf16x4*)dst)[i] = o;
    }
}

__global__ void prep_weff(const float* __restrict__ w, const float* __restrict__ dv,
                          bf16* __restrict__ weffT) {
    __shared__ float wk[256];
    __shared__ float dd[256];
    int k = blockIdx.x, j = threadIdx.x;
    dd[j] = fminf(fmaxf(dv[j], 0.0f), 1.0f);
    wk[j] = w[k * 256 + j];
    __syncthreads();
    float s = 0.0f;
#pragma unroll 8
    for (int c = 0; c < 256; ++c) s += wk[c] * dd[c] * w[j * 256 + c];
    weffT[j * 256 + k] = (bf16)s;
}

// ---------- fc_in GEMM: h0 = x @ fcw^T + b ----------
__launch_bounds__(256, 3)
__global__ void gemm_fcin(const bf16* __restrict__ xb, const bf16* __restrict__ fcwb,
                          const float* __restrict__ fcb, float* __restrict__ hf,
                          bf16* __restrict__ hb, bf16* __restrict__ hT) {
    __shared__ __align__(16) bf16 Bs[2 * 4096];
    int t = threadIdx.x, lane = t & 63, wv = t >> 6;
    int row0 = blockIdx.y * 128;   // flattened b*1024+n
    int col0 = blockIdx.x * 64;
    f32x4 acc[2][4] = {};
    phase<4>(xb + (size_t)row0 * 256, 256, fcwb + (size_t)col0 * 256, 256, Bs, acc, t);

    int rbase = row0 + wv * 32 + ((lane >> 4) << 2);
    int cbase = col0 + (lane & 15);
#pragma unroll
    for (int mi = 0; mi < 2; ++mi) {
        int rg = rbase + mi * 16;
#pragma unroll
        for (int ni = 0; ni < 4; ++ni) {
            int col = cbase + ni * 16;
            float bias = fcb[col];
            bf16x4 tv;
#pragma unroll
            for (int r = 0; r < 4; ++r) {
                float v = acc[mi][ni][r] + bias;
                size_t idx = (size_t)(rg + r) * 256 + col;
                hf[idx] = v;
                bf16 vb = (bf16)v;
                hb[idx] = vb;
                tv[r] = vb;
            }
            int b = rg >> 10, n = rg & 1023;
            *(bf16x4*)&hT[(((size_t)(b * 256 + col)) << 10) + n] = tv;
        }
    }
}

// ---------- fused Euler step ----------
__launch_bounds__(256, 3)
__global__ void gemm_step(const bf16* __restrict__ adjb, const bf16* __restrict__ hbp,
                          const bf16* __restrict__ hTp, const bf16* __restrict__ weffT,
                          const float* __restrict__ ahs, const bf16* __restrict__ x0b,
                          float* __restrict__ hf, bf16* __restrict__ hbn,
                          bf16* __restrict__ hTn) {
    __shared__ __align__(16) bf16 Bs[2 * 4096];
    int t = threadIdx.x, lane = t & 63, wv = t >> 6;
    // XCD-aware decode: all tiles of batch b on XCD b%8.
    int g = blockIdx.x;
    int xcd = g & 7, rest = g >> 3;
    int xy = rest & 31;
    int b = (rest >> 5) * 8 + xcd;
    int d0 = (xy & 3) * 64;
    int n0 = (xy >> 2) * 128;
    f32x4 acc[2][4] = {};

    // phase 1: (0.5*sig(a)*adj)[n0:,:] @ h[b]  via hT  (K=1024)
    phase<16>(adjb + (size_t)n0 * 1024, 1024,
              hTp + ((size_t)(b * 256 + d0)) * 1024, 1024, Bs, acc, t);
    // phase 2: h[b][n0:,:] @ w_eff  (K=256)
    phase<4>(hbp + ((size_t)(b * 1024 + n0)) * 256, 256,
             weffT + (size_t)d0 * 256, 256, Bs, acc, t);

    const float dt = 0.125f;
    int rb = wv * 32 + ((lane >> 4) << 2);
    int cb = d0 + (lane & 15);
#pragma unroll
    for (int mi = 0; mi < 2; ++mi) {
        int nr = n0 + rb + mi * 16;
#pragma unroll
        for (int ni = 0; ni < 4; ++ni) {
            int col = cb + ni * 16;
            bf16x4 tv;
#pragma unroll
            for (int r = 0; r < 4; ++r) {
                int node = nr + r;
                size_t idx = (((size_t)b << 10) + node) * 256 + col;
                float hold = hf[idx];
                float x0v = (float)x0b[idx];
                float f = acc[mi][ni][r] - (ahs[node] + 1.0f) * hold + x0v;
                float hv = hold + dt * f;
                hf[idx] = hv;
                bf16 vb = (bf16)hv;
                hbn[idx] = vb;
                tv[r] = vb;
            }
            *(bf16x4*)&hTn[(((size_t)(b * 256 + col)) << 10) + nr] = tv;
        }
    }
}

extern "C" void kernel_launch(void* const* d_in, const int* in_sizes, int n_in,
                              void* d_out, int out_size, void* d_ws, size_t ws_size,
                              hipStream_t stream) {
    const float* x     = (const float*)d_in[0];
    const float* adj   = (const float*)d_in[1];
    const float* alpha = (const float*)d_in[2];
    const float* w     = (const float*)d_in[3];
    const float* dvec  = (const float*)d_in[4];
    const float* fcw   = (const float*)d_in[5];
    const float* fcb   = (const float*)d_in[6];
    float* out = (float*)d_out;   // h master (fp32), updated in place

    const size_t HB = (size_t)32 * 1024 * 256 * 2;  // 16 MiB
    char* p = (char*)d_ws;
    bf16* hb0   = (bf16*)p; p += HB;
    bf16* hb1   = (bf16*)p; p += HB;
    bf16* hT0   = (bf16*)p; p += HB;
    bf16* hT1   = (bf16*)p; p += HB;
    bf16* xb    = (bf16*)p; p += HB;
    bf16* adjb  = (bf16*)p; p += (size_t)1024 * 1024 * 2;
    bf16* fcwb  = (bf16*)p; p += 256 * 256 * 2;
    bf16* weffT = (bf16*)p; p += 256 * 256 * 2;
    float* ahs  = (float*)p; p += 1024 * 4;

    prep_alpha<<<4, 256, 0, stream>>>(alpha, ahs);
    prep_adj<<<1024, 256, 0, stream>>>(adj, ahs, adjb);
    prep_weff<<<256, 256, 0, stream>>>(w, dvec, weffT);
    cast_f32_bf16x4<<<8192, 256, 0, stream>>>(x, xb, 2097152);
    cast_f32_bf16x4<<<64, 256, 0, stream>>>(fcw, fcwb, 16384);

    gemm_fcin<<<dim3(4, 256), 256, 0, stream>>>(xb, fcwb, fcb, out, hb0, hT0);

    bf16* hb[2] = {hb0, hb1};
    bf16* hT[2] = {hT0, hT1};
    int cur = 0;
    for (int s = 0; s < 8; ++s) {
        gemm_step<<<1024, 256, 0, stream>>>(
            adjb, hb[cur], hT[cur], weffT, ahs, xb, out, hb[cur ^ 1], hT[cur ^ 1]);
        cur ^= 1;
    }
}

// Round 4
// 457.165 us; speedup vs baseline: 1.1289x; 1.1289x over previous
//
#include <hip/hip_runtime.h>
#include <hip/hip_bf16.h>
#include <stdint.h>

typedef __bf16 bf16;
typedef __bf16 bf16x8 __attribute__((ext_vector_type(8)));
typedef __bf16 bf16x4 __attribute__((ext_vector_type(4)));
typedef float f32x4 __attribute__((ext_vector_type(4)));

// Tile: BM=128 (4 waves x 32 rows), BN=64, BK=64.
// BOTH operands via global_load_lds (XOR-swizzled source, linear LDS dest,
// swizzled ds_read). Double-buffered, counted vmcnt(6), raw s_barrier --
// next tile's stage stays in flight across barriers (no vmcnt(0) drain).

__device__ __forceinline__ void gload_lds16(const bf16* g, bf16* l) {
    __builtin_amdgcn_global_load_lds(
        (const __attribute__((address_space(1))) void*)g,
        (__attribute__((address_space(3))) void*)l, 16, 0, 0);
}

// 128x64 A tile: 1024 16B chunks, 4/thread.
__device__ __forceinline__ void stageA(const bf16* __restrict__ g, int lda,
                                       bf16* l, int t) {
#pragma unroll
    for (int i = 0; i < 4; ++i) {
        int c = (i << 8) + t;
        int row = c >> 3, slot = c & 7;
        gload_lds16(g + (size_t)row * lda + ((slot ^ (row & 7)) << 3), l + c * 8);
    }
}
// 64x64 B tile: 512 chunks, 2/thread.
__device__ __forceinline__ void stageB(const bf16* __restrict__ g, int ldb,
                                       bf16* l, int t) {
#pragma unroll
    for (int i = 0; i < 2; ++i) {
        int c = (i << 8) + t;
        int row = c >> 3, slot = c & 7;
        gload_lds16(g + (size_t)row * ldb + ((slot ^ (row & 7)) << 3), l + c * 8);
    }
}

// MFMA one 64-K tile from swizzled LDS buffers.
__device__ __forceinline__ void mma_tile(const bf16* A, const bf16* B,
                                         f32x4 acc[2][4], int lane, int wv) {
    const int r0 = wv * 32 + (lane & 15);
    const int kq = lane >> 4;
    bf16x8 a[2][2], b[4][2];
#pragma unroll
    for (int mi = 0; mi < 2; ++mi) {
        int rA = r0 + mi * 16;
#pragma unroll
        for (int kk = 0; kk < 2; ++kk) {
            int kc = kk * 4 + kq;
            a[mi][kk] = *(const bf16x8*)&A[rA * 64 + ((kc ^ (rA & 7)) << 3)];
        }
    }
#pragma unroll
    for (int ni = 0; ni < 4; ++ni) {
        int rB = ni * 16 + (lane & 15);
#pragma unroll
        for (int kk = 0; kk < 2; ++kk) {
            int kc = kk * 4 + kq;
            b[ni][kk] = *(const bf16x8*)&B[rB * 64 + ((kc ^ (rB & 7)) << 3)];
        }
    }
#pragma unroll
    for (int kk = 0; kk < 2; ++kk)
#pragma unroll
        for (int mi = 0; mi < 2; ++mi)
#pragma unroll
            for (int ni = 0; ni < 4; ++ni)
                acc[mi][ni] = __builtin_amdgcn_mfma_f32_16x16x32_bf16(
                    a[mi][kk], b[ni][kk], acc[mi][ni], 0, 0, 0);
}

// Counted-vmcnt pipelined K-loop. tadr(i) -> operand pointers for tile i.
template <int NT, typename F>
__device__ __forceinline__ void run_pipeline(F tadr, bf16 (*As)[8192],
                                             bf16 (*Bs)[4096], f32x4 acc[2][4],
                                             int t, int lane, int wv) {
    {
        const bf16 *Ag, *Bg; int lda, ldb;
        tadr(0, Ag, lda, Bg, ldb);
        stageA(Ag, lda, As[0], t);
        stageB(Bg, ldb, Bs[0], t);
    }
#pragma unroll 1
    for (int i = 0; i < NT; ++i) {
        if (i + 1 < NT) {
            const bf16 *Ag, *Bg; int lda, ldb;
            tadr(i + 1, Ag, lda, Bg, ldb);
            stageA(Ag, lda, As[(i + 1) & 1], t);
            stageB(Bg, ldb, Bs[(i + 1) & 1], t);
            asm volatile("s_waitcnt vmcnt(6)" ::: "memory");  // tile i landed
        } else {
            asm volatile("s_waitcnt vmcnt(0)" ::: "memory");
        }
        __builtin_amdgcn_s_barrier();                 // buffers[i&1] ready
        asm volatile("" ::: "memory");
        mma_tile(As[i & 1], Bs[i & 1], acc, lane, wv);
        asm volatile("" ::: "memory");
        __builtin_amdgcn_s_barrier();                 // reads of [i&1] closed
    }
}

// ---------- prep kernels ----------
__global__ void prep_alpha(const float* __restrict__ a, float* __restrict__ out) {
    int i = blockIdx.x * blockDim.x + threadIdx.x;
    if (i < 1024) out[i] = 0.5f / (1.0f + __expf(-a[i]));
}

__global__ void prep_adj(const float* __restrict__ adj, const float* __restrict__ ahs,
                         bf16* __restrict__ adjb) {
    int i = blockIdx.x * blockDim.x + threadIdx.x;
    int row = i >> 8;
    float s = ahs[row];
    float4 v = ((const float4*)adj)[i];
    bf16x4 o = {(bf16)(s * v.x), (bf16)(s * v.y), (bf16)(s * v.z), (bf16)(s * v.w)};
    ((bf16x4*)adjb)[i] = o;
}

__global__ void cast_f32_bf16x4(const float* __restrict__ src, bf16* __restrict__ dst,
                                int n4) {
    int i = blockIdx.x * blockDim.x + threadIdx.x;
    if (i < n4) {
        float4 v = ((const float4*)src)[i];
        bf16x4 o = {(bf16)v.x, (bf16)v.y, (bf16)v.z, (bf16)v.w};
        ((bf16x4*)dst)[i] = o;
    }
}

__global__ void prep_weff(const float* __restrict__ w, const float* __restrict__ dv,
                          bf16* __restrict__ weffT) {
    __shared__ float wk[256];
    __shared__ float dd[256];
    int k = blockIdx.x, j = threadIdx.x;
    dd[j] = fminf(fmaxf(dv[j], 0.0f), 1.0f);
    wk[j] = w[k * 256 + j];
    __syncthreads();
    float s = 0.0f;
#pragma unroll 8
    for (int c = 0; c < 256; ++c) s += wk[c] * dd[c] * w[j * 256 + c];
    weffT[j * 256 + k] = (bf16)s;
}

// ---------- fc_in GEMM: h0 = x @ fcw^T + b ----------
__launch_bounds__(256, 2)
__global__ void gemm_fcin(const bf16* __restrict__ xb, const bf16* __restrict__ fcwb,
                          const float* __restrict__ fcb, float* __restrict__ hf,
                          bf16* __restrict__ hb, bf16* __restrict__ hT) {
    __shared__ __align__(16) bf16 As[2][8192];
    __shared__ __align__(16) bf16 Bs[2][4096];
    int t = threadIdx.x, lane = t & 63, wv = t >> 6;
    int row0 = blockIdx.y * 128;   // flattened b*1024+n
    int col0 = blockIdx.x * 64;
    f32x4 acc[2][4] = {};
    const bf16* Ab = xb + (size_t)row0 * 256;
    const bf16* Bb = fcwb + (size_t)col0 * 256;
    auto tadr = [&](int i, const bf16*& Ag, int& lda, const bf16*& Bg, int& ldb) {
        Ag = Ab + i * 64; lda = 256;
        Bg = Bb + i * 64; ldb = 256;
    };
    run_pipeline<4>(tadr, As, Bs, acc, t, lane, wv);

    int rbase = row0 + wv * 32 + ((lane >> 4) << 2);
    int cbase = col0 + (lane & 15);
#pragma unroll
    for (int mi = 0; mi < 2; ++mi) {
        int rg = rbase + mi * 16;
#pragma unroll
        for (int ni = 0; ni < 4; ++ni) {
            int col = cbase + ni * 16;
            float bias = fcb[col];
            bf16x4 tv;
#pragma unroll
            for (int r = 0; r < 4; ++r) {
                float v = acc[mi][ni][r] + bias;
                size_t idx = (size_t)(rg + r) * 256 + col;
                hf[idx] = v;
                bf16 vb = (bf16)v;
                hb[idx] = vb;
                tv[r] = vb;
            }
            int b = rg >> 10, n = rg & 1023;
            *(bf16x4*)&hT[(((size_t)(b * 256 + col)) << 10) + n] = tv;
        }
    }
}

// ---------- fused Euler step ----------
__launch_bounds__(256, 2)
__global__ void gemm_step(const bf16* __restrict__ adjb, const bf16* __restrict__ hbp,
                          const bf16* __restrict__ hTp, const bf16* __restrict__ weffT,
                          const float* __restrict__ ahs, const bf16* __restrict__ x0b,
                          float* __restrict__ hf, bf16* __restrict__ hbn,
                          bf16* __restrict__ hTn) {
    __shared__ __align__(16) bf16 As[2][8192];
    __shared__ __align__(16) bf16 Bs[2][4096];
    int t = threadIdx.x, lane = t & 63, wv = t >> 6;
    // XCD-aware decode: all tiles of batch b on XCD b%8.
    int g = blockIdx.x;
    int xcd = g & 7, rest = g >> 3;
    int xy = rest & 31;
    int b = (rest >> 5) * 8 + xcd;
    int d0 = (xy & 3) * 64;
    int n0 = (xy >> 2) * 128;
    f32x4 acc[2][4] = {};

    const bf16* A1 = adjb + (size_t)n0 * 1024;                  // K=1024, 16 tiles
    const bf16* B1 = hTp + ((size_t)(b * 256 + d0)) * 1024;
    const bf16* A2 = hbp + ((size_t)(b * 1024 + n0)) * 256;     // K=256, 4 tiles
    const bf16* B2 = weffT + (size_t)d0 * 256;
    auto tadr = [&](int i, const bf16*& Ag, int& lda, const bf16*& Bg, int& ldb) {
        if (i < 16) {
            Ag = A1 + i * 64; lda = 1024;
            Bg = B1 + i * 64; ldb = 1024;
        } else {
            Ag = A2 + (i - 16) * 64; lda = 256;
            Bg = B2 + (i - 16) * 64; ldb = 256;
        }
    };
    run_pipeline<20>(tadr, As, Bs, acc, t, lane, wv);

    const float dt = 0.125f;
    int rb = wv * 32 + ((lane >> 4) << 2);
    int cb = d0 + (lane & 15);
#pragma unroll
    for (int mi = 0; mi < 2; ++mi) {
        int nr = n0 + rb + mi * 16;
#pragma unroll
        for (int ni = 0; ni < 4; ++ni) {
            int col = cb + ni * 16;
            bf16x4 tv;
#pragma unroll
            for (int r = 0; r < 4; ++r) {
                int node = nr + r;
                size_t idx = (((size_t)b << 10) + node) * 256 + col;
                float hold = hf[idx];
                float x0v = (float)x0b[idx];
                float f = acc[mi][ni][r] - (ahs[node] + 1.0f) * hold + x0v;
                float hv = hold + dt * f;
                hf[idx] = hv;
                bf16 vb = (bf16)hv;
                hbn[idx] = vb;
                tv[r] = vb;
            }
            *(bf16x4*)&hTn[(((size_t)(b * 256 + col)) << 10) + nr] = tv;
        }
    }
}

extern "C" void kernel_launch(void* const* d_in, const int* in_sizes, int n_in,
                              void* d_out, int out_size, void* d_ws, size_t ws_size,
                              hipStream_t stream) {
    const float* x     = (const float*)d_in[0];
    const float* adj   = (const float*)d_in[1];
    const float* alpha = (const float*)d_in[2];
    const float* w     = (const float*)d_in[3];
    const float* dvec  = (const float*)d_in[4];
    const float* fcw   = (const float*)d_in[5];
    const float* fcb   = (const float*)d_in[6];
    float* out = (float*)d_out;   // h master (fp32), updated in place

    const size_t HB = (size_t)32 * 1024 * 256 * 2;  // 16 MiB
    char* p = (char*)d_ws;
    bf16* hb0   = (bf16*)p; p += HB;
    bf16* hb1   = (bf16*)p; p += HB;
    bf16* hT0   = (bf16*)p; p += HB;
    bf16* hT1   = (bf16*)p; p += HB;
    bf16* xb    = (bf16*)p; p += HB;
    bf16* adjb  = (bf16*)p; p += (size_t)1024 * 1024 * 2;
    bf16* fcwb  = (bf16*)p; p += 256 * 256 * 2;
    bf16* weffT = (bf16*)p; p += 256 * 256 * 2;
    float* ahs  = (float*)p; p += 1024 * 4;

    prep_alpha<<<4, 256, 0, stream>>>(alpha, ahs);
    prep_adj<<<1024, 256, 0, stream>>>(adj, ahs, adjb);
    prep_weff<<<256, 256, 0, stream>>>(w, dvec, weffT);
    cast_f32_bf16x4<<<8192, 256, 0, stream>>>(x, xb, 2097152);
    cast_f32_bf16x4<<<64, 256, 0, stream>>>(fcw, fcwb, 16384);

    gemm_fcin<<<dim3(4, 256), 256, 0, stream>>>(xb, fcwb, fcb, out, hb0, hT0);

    bf16* hb[2] = {hb0, hb1};
    bf16* hT[2] = {hT0, hT1};
    int cur = 0;
    for (int s = 0; s < 8; ++s) {
        gemm_step<<<1024, 256, 0, stream>>>(
            adjb, hb[cur], hT[cur], weffT, ahs, xb, out, hb[cur ^ 1], hT[cur ^ 1]);
        cur ^= 1;
    }
}

// Round 5
// 450.912 us; speedup vs baseline: 1.1446x; 1.0139x over previous
//
#include <hip/hip_runtime.h>
#include <hip/hip_bf16.h>
#include <stdint.h>

typedef __bf16 bf16;
typedef __bf16 bf16x8 __attribute__((ext_vector_type(8)));
typedef __bf16 bf16x4 __attribute__((ext_vector_type(4)));
typedef float f32x4 __attribute__((ext_vector_type(4)));

// Tile: BM=128 (4 waves x 32 rows), BN=64, BK=64.
// Both operands via global_load_lds (XOR-swizzled source, linear LDS dest,
// swizzled ds_read). Triple-buffered, DEPTH-2 prefetch: vmcnt(12) keeps two
// tiles' loads in flight across barriers. Master h = compensated bf16
// (h_hi + h_lo); fp32 out written only on the last step.

__device__ __forceinline__ void gload_lds16(const bf16* g, bf16* l) {
    __builtin_amdgcn_global_load_lds(
        (const __attribute__((address_space(1))) void*)g,
        (__attribute__((address_space(3))) void*)l, 16, 0, 0);
}

// 128x64 A tile: 1024 16B chunks, 4/thread.
__device__ __forceinline__ void stageA(const bf16* __restrict__ g, int lda,
                                       bf16* l, int t) {
#pragma unroll
    for (int i = 0; i < 4; ++i) {
        int c = (i << 8) + t;
        int row = c >> 3, slot = c & 7;
        gload_lds16(g + (size_t)row * lda + ((slot ^ (row & 7)) << 3), l + c * 8);
    }
}
// 64x64 B tile: 512 chunks, 2/thread.
__device__ __forceinline__ void stageB(const bf16* __restrict__ g, int ldb,
                                       bf16* l, int t) {
#pragma unroll
    for (int i = 0; i < 2; ++i) {
        int c = (i << 8) + t;
        int row = c >> 3, slot = c & 7;
        gload_lds16(g + (size_t)row * ldb + ((slot ^ (row & 7)) << 3), l + c * 8);
    }
}

// MFMA one 64-K tile from swizzled LDS buffers.
__device__ __forceinline__ void mma_tile(const bf16* A, const bf16* B,
                                         f32x4 acc[2][4], int lane, int wv) {
    const int r0 = wv * 32 + (lane & 15);
    const int kq = lane >> 4;
    bf16x8 a[2][2], b[4][2];
#pragma unroll
    for (int mi = 0; mi < 2; ++mi) {
        int rA = r0 + mi * 16;
#pragma unroll
        for (int kk = 0; kk < 2; ++kk) {
            int kc = kk * 4 + kq;
            a[mi][kk] = *(const bf16x8*)&A[rA * 64 + ((kc ^ (rA & 7)) << 3)];
        }
    }
#pragma unroll
    for (int ni = 0; ni < 4; ++ni) {
        int rB = ni * 16 + (lane & 15);
#pragma unroll
        for (int kk = 0; kk < 2; ++kk) {
            int kc = kk * 4 + kq;
            b[ni][kk] = *(const bf16x8*)&B[rB * 64 + ((kc ^ (rB & 7)) << 3)];
        }
    }
#pragma unroll
    for (int kk = 0; kk < 2; ++kk)
#pragma unroll
        for (int mi = 0; mi < 2; ++mi)
#pragma unroll
            for (int ni = 0; ni < 4; ++ni)
                acc[mi][ni] = __builtin_amdgcn_mfma_f32_16x16x32_bf16(
                    a[mi][kk], b[ni][kk], acc[mi][ni], 0, 0, 0);
}

// Depth-2 counted-vmcnt pipeline, 3 LDS buffers.
template <int NT, typename F>
__device__ __forceinline__ void run_pipeline(F tadr, bf16 (*As)[8192],
                                             bf16 (*Bs)[4096], f32x4 acc[2][4],
                                             int t, int lane, int wv) {
    {
        const bf16 *Ag, *Bg; int lda, ldb;
        tadr(0, Ag, lda, Bg, ldb);
        stageA(Ag, lda, As[0], t);
        stageB(Bg, ldb, Bs[0], t);
        if (NT > 1) {
            tadr(1, Ag, lda, Bg, ldb);
            stageA(Ag, lda, As[1], t);
            stageB(Bg, ldb, Bs[1], t);
        }
    }
    int cur = 0, pre = 2;
#pragma unroll 1
    for (int i = 0; i < NT; ++i) {
        if (i + 2 < NT) {
            const bf16 *Ag, *Bg; int lda, ldb;
            tadr(i + 2, Ag, lda, Bg, ldb);
            stageA(Ag, lda, As[pre], t);
            stageB(Bg, ldb, Bs[pre], t);
            asm volatile("s_waitcnt vmcnt(12)" ::: "memory");  // tile i landed
        } else if (i + 1 < NT) {
            asm volatile("s_waitcnt vmcnt(6)" ::: "memory");
        } else {
            asm volatile("s_waitcnt vmcnt(0)" ::: "memory");
        }
        __builtin_amdgcn_s_barrier();                 // buffers[cur] ready
        __builtin_amdgcn_s_setprio(1);
        mma_tile(As[cur], Bs[cur], acc, lane, wv);
        __builtin_amdgcn_s_setprio(0);
        __builtin_amdgcn_s_barrier();                 // reads of [cur] closed
        cur = (cur == 2) ? 0 : cur + 1;
        pre = (pre == 2) ? 0 : pre + 1;
    }
}

// ---------- prep kernels ----------
__global__ void prep_alpha(const float* __restrict__ a, float* __restrict__ out) {
    int i = blockIdx.x * blockDim.x + threadIdx.x;
    if (i < 1024) out[i] = 0.5f / (1.0f + __expf(-a[i]));
}

__global__ void prep_adj(const float* __restrict__ adj, const float* __restrict__ ahs,
                         bf16* __restrict__ adjb) {
    int i = blockIdx.x * blockDim.x + threadIdx.x;
    int row = i >> 8;
    float s = ahs[row];
    float4 v = ((const float4*)adj)[i];
    bf16x4 o = {(bf16)(s * v.x), (bf16)(s * v.y), (bf16)(s * v.z), (bf16)(s * v.w)};
    ((bf16x4*)adjb)[i] = o;
}

__global__ void cast_f32_bf16x4(const float* __restrict__ src, bf16* __restrict__ dst,
                                int n4) {
    int i = blockIdx.x * blockDim.x + threadIdx.x;
    if (i < n4) {
        float4 v = ((const float4*)src)[i];
        bf16x4 o = {(bf16)v.x, (bf16)v.y, (bf16)v.z, (bf16)v.w};
        ((bf16x4*)dst)[i] = o;
    }
}

__global__ void prep_weff(const float* __restrict__ w, const float* __restrict__ dv,
                          bf16* __restrict__ weffT) {
    __shared__ float wk[256];
    __shared__ float dd[256];
    int k = blockIdx.x, j = threadIdx.x;
    dd[j] = fminf(fmaxf(dv[j], 0.0f), 1.0f);
    wk[j] = w[k * 256 + j];
    __syncthreads();
    float s = 0.0f;
#pragma unroll 8
    for (int c = 0; c < 256; ++c) s += wk[c] * dd[c] * w[j * 256 + c];
    weffT[j * 256 + k] = (bf16)s;
}

// ---------- fc_in GEMM: h0 = x @ fcw^T + b ----------
__launch_bounds__(256, 2)
__global__ void gemm_fcin(const bf16* __restrict__ xb, const bf16* __restrict__ fcwb,
                          const float* __restrict__ fcb,
                          bf16* __restrict__ hb, bf16* __restrict__ hT,
                          bf16* __restrict__ hlo) {
    __shared__ __align__(16) bf16 As[3][8192];
    __shared__ __align__(16) bf16 Bs[3][4096];
    int t = threadIdx.x, lane = t & 63, wv = t >> 6;
    int row0 = blockIdx.y * 128;   // flattened b*1024+n
    int col0 = blockIdx.x * 64;
    f32x4 acc[2][4] = {};
    const bf16* Ab = xb + (size_t)row0 * 256;
    const bf16* Bb = fcwb + (size_t)col0 * 256;
    auto tadr = [&](int i, const bf16*& Ag, int& lda, const bf16*& Bg, int& ldb) {
        Ag = Ab + i * 64; lda = 256;
        Bg = Bb + i * 64; ldb = 256;
    };
    run_pipeline<4>(tadr, As, Bs, acc, t, lane, wv);

    int rbase = row0 + wv * 32 + ((lane >> 4) << 2);
    int cbase = col0 + (lane & 15);
#pragma unroll
    for (int mi = 0; mi < 2; ++mi) {
        int rg = rbase + mi * 16;
#pragma unroll
        for (int ni = 0; ni < 4; ++ni) {
            int col = cbase + ni * 16;
            float bias = fcb[col];
            bf16x4 tv;
#pragma unroll
            for (int r = 0; r < 4; ++r) {
                float v = acc[mi][ni][r] + bias;
                size_t idx = (size_t)(rg + r) * 256 + col;
                bf16 hi = (bf16)v;
                bf16 lo = (bf16)(v - (float)hi);
                hb[idx] = hi;
                hlo[idx] = lo;
                tv[r] = hi;
            }
            int b = rg >> 10, n = rg & 1023;
            *(bf16x4*)&hT[(((size_t)(b * 256 + col)) << 10) + n] = tv;
        }
    }
}

// ---------- fused Euler step ----------
template <bool LAST>
__launch_bounds__(256, 2)
__global__ void gemm_step(const bf16* __restrict__ adjb, const bf16* __restrict__ hbp,
                          const bf16* __restrict__ hTp, const bf16* __restrict__ weffT,
                          const float* __restrict__ ahs, const bf16* __restrict__ x0b,
                          bf16* __restrict__ hlo, bf16* __restrict__ hbn,
                          bf16* __restrict__ hTn, float* __restrict__ out) {
    __shared__ __align__(16) bf16 As[3][8192];
    __shared__ __align__(16) bf16 Bs[3][4096];
    int t = threadIdx.x, lane = t & 63, wv = t >> 6;
    // XCD-aware decode: all tiles of batch b on XCD b%8.
    int g = blockIdx.x;
    int xcd = g & 7, rest = g >> 3;
    int xy = rest & 31;
    int b = (rest >> 5) * 8 + xcd;
    int d0 = (xy & 3) * 64;
    int n0 = (xy >> 2) * 128;
    f32x4 acc[2][4] = {};

    const bf16* A1 = adjb + (size_t)n0 * 1024;                  // K=1024, 16 tiles
    const bf16* B1 = hTp + ((size_t)(b * 256 + d0)) * 1024;
    const bf16* A2 = hbp + ((size_t)(b * 1024 + n0)) * 256;     // K=256, 4 tiles
    const bf16* B2 = weffT + (size_t)d0 * 256;
    auto tadr = [&](int i, const bf16*& Ag, int& lda, const bf16*& Bg, int& ldb) {
        if (i < 16) {
            Ag = A1 + i * 64; lda = 1024;
            Bg = B1 + i * 64; ldb = 1024;
        } else {
            Ag = A2 + (i - 16) * 64; lda = 256;
            Bg = B2 + (i - 16) * 64; ldb = 256;
        }
    };
    run_pipeline<20>(tadr, As, Bs, acc, t, lane, wv);

    const float dt = 0.125f;
    int rb = wv * 32 + ((lane >> 4) << 2);
    int cb = d0 + (lane & 15);
#pragma unroll
    for (int mi = 0; mi < 2; ++mi) {
        int nr = n0 + rb + mi * 16;
#pragma unroll
        for (int ni = 0; ni < 4; ++ni) {
            int col = cb + ni * 16;
            bf16x4 tv;
#pragma unroll
            for (int r = 0; r < 4; ++r) {
                int node = nr + r;
                size_t idx = (((size_t)b << 10) + node) * 256 + col;
                float hi = (float)hbp[idx];
                float lo = (float)hlo[idx];
                float hold = hi + lo;
                float x0v = (float)x0b[idx];
                float f = acc[mi][ni][r] - (ahs[node] + 1.0f) * hold + x0v;
                float hv = hold + dt * f;
                if (LAST) {
                    out[idx] = hv;
                } else {
                    bf16 nhi = (bf16)hv;
                    bf16 nlo = (bf16)(hv - (float)nhi);
                    hbn[idx] = nhi;
                    hlo[idx] = nlo;
                    tv[r] = nhi;
                }
            }
            if (!LAST)
                *(bf16x4*)&hTn[(((size_t)(b * 256 + col)) << 10) + nr] = tv;
        }
    }
}

extern "C" void kernel_launch(void* const* d_in, const int* in_sizes, int n_in,
                              void* d_out, int out_size, void* d_ws, size_t ws_size,
                              hipStream_t stream) {
    const float* x     = (const float*)d_in[0];
    const float* adj   = (const float*)d_in[1];
    const float* alpha = (const float*)d_in[2];
    const float* w     = (const float*)d_in[3];
    const float* dvec  = (const float*)d_in[4];
    const float* fcw   = (const float*)d_in[5];
    const float* fcb   = (const float*)d_in[6];
    float* out = (float*)d_out;   // fp32 h, written by the LAST step only

    const size_t HB = (size_t)32 * 1024 * 256 * 2;  // 16 MiB
    char* p = (char*)d_ws;
    bf16* hb0   = (bf16*)p; p += HB;
    bf16* hb1   = (bf16*)p; p += HB;
    bf16* hT0   = (bf16*)p; p += HB;
    bf16* hT1   = (bf16*)p; p += HB;
    bf16* xb    = (bf16*)p; p += HB;
    bf16* hlo   = (bf16*)p; p += HB;   // single in-place residual buffer
    bf16* adjb  = (bf16*)p; p += (size_t)1024 * 1024 * 2;
    bf16* fcwb  = (bf16*)p; p += 256 * 256 * 2;
    bf16* weffT = (bf16*)p; p += 256 * 256 * 2;
    float* ahs  = (float*)p; p += 1024 * 4;

    prep_alpha<<<4, 256, 0, stream>>>(alpha, ahs);
    prep_adj<<<1024, 256, 0, stream>>>(adj, ahs, adjb);
    prep_weff<<<256, 256, 0, stream>>>(w, dvec, weffT);
    cast_f32_bf16x4<<<8192, 256, 0, stream>>>(x, xb, 2097152);
    cast_f32_bf16x4<<<64, 256, 0, stream>>>(fcw, fcwb, 16384);

    gemm_fcin<<<dim3(4, 256), 256, 0, stream>>>(xb, fcwb, fcb, hb0, hT0, hlo);

    bf16* hb[2] = {hb0, hb1};
    bf16* hT[2] = {hT0, hT1};
    int cur = 0;
    for (int s = 0; s < 8; ++s) {
        if (s < 7)
            gemm_step<false><<<1024, 256, 0, stream>>>(
                adjb, hb[cur], hT[cur], weffT, ahs, xb, hlo,
                hb[cur ^ 1], hT[cur ^ 1], out);
        else
            gemm_step<true><<<1024, 256, 0, stream>>>(
                adjb, hb[cur], hT[cur], weffT, ahs, xb, hlo,
                hb[cur ^ 1], hT[cur ^ 1], out);
        cur ^= 1;
    }
}

// Round 6
// 432.339 us; speedup vs baseline: 1.1938x; 1.0430x over previous
//
#include <hip/hip_runtime.h>
#include <hip/hip_bf16.h>
#include <stdint.h>

typedef __bf16 bf16;
typedef __bf16 bf16x8 __attribute__((ext_vector_type(8)));
typedef __bf16 bf16x4 __attribute__((ext_vector_type(4)));
typedef float f32x4 __attribute__((ext_vector_type(4)));

__device__ __forceinline__ void gload_lds16(const bf16* g, bf16* l) {
    __builtin_amdgcn_global_load_lds(
        (const __attribute__((address_space(1))) void*)g,
        (__attribute__((address_space(3))) void*)l, 16, 0, 0);
}

// ---------------- step kernel machinery: 256x128 tile, 512 threads ----------
// Stage ROWS x 64 bf16 tile; XOR-swizzled global source, linear LDS dest.
template <int ROWS>
__device__ __forceinline__ void stageRows(const bf16* __restrict__ g, int ld,
                                          bf16* l, int t) {
#pragma unroll
    for (int i = 0; i < ROWS * 8 / 512; ++i) {
        int c = i * 512 + t;
        int row = c >> 3, slot = c & 7;
        gload_lds16(g + (size_t)row * ld + ((slot ^ (row & 7)) << 3), l + c * 8);
    }
}

// 8 waves as 4x2; wave tile 64x64 = acc[4][4] of 16x16x32.
__device__ __forceinline__ void mma_fat(const bf16* A, const bf16* B,
                                        f32x4 acc[4][4], int lane, int wm, int wn) {
    const int l15 = lane & 15;
    const int kq = lane >> 4;            // 0..3
#pragma unroll
    for (int kk = 0; kk < 2; ++kk) {
        int kc = kk * 4 + kq;            // 16B slot 0..7
        bf16x8 a[4], b[4];
#pragma unroll
        for (int mi = 0; mi < 4; ++mi) {
            int rA = wm * 64 + mi * 16 + l15;
            a[mi] = *(const bf16x8*)&A[rA * 64 + ((kc ^ (rA & 7)) << 3)];
        }
#pragma unroll
        for (int ni = 0; ni < 4; ++ni) {
            int rB = wn * 64 + ni * 16 + l15;
            b[ni] = *(const bf16x8*)&B[rB * 64 + ((kc ^ (rB & 7)) << 3)];
        }
#pragma unroll
        for (int mi = 0; mi < 4; ++mi)
#pragma unroll
            for (int ni = 0; ni < 4; ++ni)
                acc[mi][ni] = __builtin_amdgcn_mfma_f32_16x16x32_bf16(
                    a[mi], b[ni], acc[mi][ni], 0, 0, 0);
    }
}

// Depth-2 counted-vmcnt pipeline, 3 LDS buffers. 6 loads/thread/tile.
template <int NT, typename F>
__device__ __forceinline__ void run_pipe2(F tadr, bf16 (*As)[16384], bf16 (*Bs)[8192],
                                          f32x4 acc[4][4], int t, int lane,
                                          int wm, int wn) {
    {
        const bf16 *Ag, *Bg; int lda, ldb;
        tadr(0, Ag, lda, Bg, ldb);
        stageRows<256>(Ag, lda, As[0], t);
        stageRows<128>(Bg, ldb, Bs[0], t);
        tadr(1, Ag, lda, Bg, ldb);
        stageRows<256>(Ag, lda, As[1], t);
        stageRows<128>(Bg, ldb, Bs[1], t);
    }
    int cur = 0, pre = 2;
#pragma unroll 1
    for (int i = 0; i < NT; ++i) {
        if (i + 2 < NT) {
            const bf16 *Ag, *Bg; int lda, ldb;
            tadr(i + 2, Ag, lda, Bg, ldb);
            stageRows<256>(Ag, lda, As[pre], t);
            stageRows<128>(Bg, ldb, Bs[pre], t);
            asm volatile("s_waitcnt vmcnt(12)" ::: "memory");  // tile i landed
        } else if (i + 1 < NT) {
            asm volatile("s_waitcnt vmcnt(6)" ::: "memory");
        } else {
            asm volatile("s_waitcnt vmcnt(0)" ::: "memory");
        }
        __builtin_amdgcn_s_barrier();                 // buffers[cur] ready
        __builtin_amdgcn_s_setprio(1);
        mma_fat(As[cur], Bs[cur], acc, lane, wm, wn);
        __builtin_amdgcn_s_setprio(0);
        __builtin_amdgcn_s_barrier();                 // reads of [cur] closed
        cur = (cur == 2) ? 0 : cur + 1;
        pre = (pre == 2) ? 0 : pre + 1;
    }
}

// ---------------- fc_in machinery (256 threads, 128x64 tile) ---------------
__device__ __forceinline__ void stageA(const bf16* __restrict__ g, int lda,
                                       bf16* l, int t) {
#pragma unroll
    for (int i = 0; i < 4; ++i) {
        int c = (i << 8) + t;
        int row = c >> 3, slot = c & 7;
        gload_lds16(g + (size_t)row * lda + ((slot ^ (row & 7)) << 3), l + c * 8);
    }
}
__device__ __forceinline__ void stageB(const bf16* __restrict__ g, int ldb,
                                       bf16* l, int t) {
#pragma unroll
    for (int i = 0; i < 2; ++i) {
        int c = (i << 8) + t;
        int row = c >> 3, slot = c & 7;
        gload_lds16(g + (size_t)row * ldb + ((slot ^ (row & 7)) << 3), l + c * 8);
    }
}

__device__ __forceinline__ void mma_tile(const bf16* A, const bf16* B,
                                         f32x4 acc[2][4], int lane, int wv) {
    const int r0 = wv * 32 + (lane & 15);
    const int kq = lane >> 4;
    bf16x8 a[2][2], b[4][2];
#pragma unroll
    for (int mi = 0; mi < 2; ++mi) {
        int rA = r0 + mi * 16;
#pragma unroll
        for (int kk = 0; kk < 2; ++kk) {
            int kc = kk * 4 + kq;
            a[mi][kk] = *(const bf16x8*)&A[rA * 64 + ((kc ^ (rA & 7)) << 3)];
        }
    }
#pragma unroll
    for (int ni = 0; ni < 4; ++ni) {
        int rB = ni * 16 + (lane & 15);
#pragma unroll
        for (int kk = 0; kk < 2; ++kk) {
            int kc = kk * 4 + kq;
            b[ni][kk] = *(const bf16x8*)&B[rB * 64 + ((kc ^ (rB & 7)) << 3)];
        }
    }
#pragma unroll
    for (int kk = 0; kk < 2; ++kk)
#pragma unroll
        for (int mi = 0; mi < 2; ++mi)
#pragma unroll
            for (int ni = 0; ni < 4; ++ni)
                acc[mi][ni] = __builtin_amdgcn_mfma_f32_16x16x32_bf16(
                    a[mi][kk], b[ni][kk], acc[mi][ni], 0, 0, 0);
}

template <int NT, typename F>
__device__ __forceinline__ void run_pipeline(F tadr, bf16 (*As)[8192],
                                             bf16 (*Bs)[4096], f32x4 acc[2][4],
                                             int t, int lane, int wv) {
    {
        const bf16 *Ag, *Bg; int lda, ldb;
        tadr(0, Ag, lda, Bg, ldb);
        stageA(Ag, lda, As[0], t);
        stageB(Bg, ldb, Bs[0], t);
        if (NT > 1) {
            tadr(1, Ag, lda, Bg, ldb);
            stageA(Ag, lda, As[1], t);
            stageB(Bg, ldb, Bs[1], t);
        }
    }
    int cur = 0, pre = 2;
#pragma unroll 1
    for (int i = 0; i < NT; ++i) {
        if (i + 2 < NT) {
            const bf16 *Ag, *Bg; int lda, ldb;
            tadr(i + 2, Ag, lda, Bg, ldb);
            stageA(Ag, lda, As[pre], t);
            stageB(Bg, ldb, Bs[pre], t);
            asm volatile("s_waitcnt vmcnt(12)" ::: "memory");
        } else if (i + 1 < NT) {
            asm volatile("s_waitcnt vmcnt(6)" ::: "memory");
        } else {
            asm volatile("s_waitcnt vmcnt(0)" ::: "memory");
        }
        __builtin_amdgcn_s_barrier();
        __builtin_amdgcn_s_setprio(1);
        mma_tile(As[cur], Bs[cur], acc, lane, wv);
        __builtin_amdgcn_s_setprio(0);
        __builtin_amdgcn_s_barrier();
        cur = (cur == 2) ? 0 : cur + 1;
        pre = (pre == 2) ? 0 : pre + 1;
    }
}

// ---------- prep kernels ----------
__global__ void prep_alpha(const float* __restrict__ a, float* __restrict__ out) {
    int i = blockIdx.x * blockDim.x + threadIdx.x;
    if (i < 1024) out[i] = 0.5f / (1.0f + __expf(-a[i]));
}

__global__ void prep_adj(const float* __restrict__ adj, const float* __restrict__ ahs,
                         bf16* __restrict__ adjb) {
    int i = blockIdx.x * blockDim.x + threadIdx.x;
    int row = i >> 8;
    float s = ahs[row];
    float4 v = ((const float4*)adj)[i];
    bf16x4 o = {(bf16)(s * v.x), (bf16)(s * v.y), (bf16)(s * v.z), (bf16)(s * v.w)};
    ((bf16x4*)adjb)[i] = o;
}

__global__ void cast_f32_bf16x4(const float* __restrict__ src, bf16* __restrict__ dst,
                                int n4) {
    int i = blockIdx.x * blockDim.x + threadIdx.x;
    if (i < n4) {
        float4 v = ((const float4*)src)[i];
        bf16x4 o = {(bf16)v.x, (bf16)v.y, (bf16)v.z, (bf16)v.w};
        ((bf16x4*)dst)[i] = o;
    }
}

__global__ void prep_weff(const float* __restrict__ w, const float* __restrict__ dv,
                          bf16* __restrict__ weffT) {
    __shared__ float wk[256];
    __shared__ float dd[256];
    int k = blockIdx.x, j = threadIdx.x;
    dd[j] = fminf(fmaxf(dv[j], 0.0f), 1.0f);
    wk[j] = w[k * 256 + j];
    __syncthreads();
    float s = 0.0f;
#pragma unroll 8
    for (int c = 0; c < 256; ++c) s += wk[c] * dd[c] * w[j * 256 + c];
    weffT[j * 256 + k] = (bf16)s;
}

// ---------- fc_in GEMM: h0 = x @ fcw^T + b ----------
__launch_bounds__(256, 2)
__global__ void gemm_fcin(const bf16* __restrict__ xb, const bf16* __restrict__ fcwb,
                          const float* __restrict__ fcb,
                          bf16* __restrict__ hb, bf16* __restrict__ hT,
                          bf16* __restrict__ hlo) {
    __shared__ __align__(16) bf16 As[3][8192];
    __shared__ __align__(16) bf16 Bs[3][4096];
    int t = threadIdx.x, lane = t & 63, wv = t >> 6;
    int row0 = blockIdx.y * 128;   // flattened b*1024+n
    int col0 = blockIdx.x * 64;
    f32x4 acc[2][4] = {};
    const bf16* Ab = xb + (size_t)row0 * 256;
    const bf16* Bb = fcwb + (size_t)col0 * 256;
    auto tadr = [&](int i, const bf16*& Ag, int& lda, const bf16*& Bg, int& ldb) {
        Ag = Ab + i * 64; lda = 256;
        Bg = Bb + i * 64; ldb = 256;
    };
    run_pipeline<4>(tadr, As, Bs, acc, t, lane, wv);

    int rbase = row0 + wv * 32 + ((lane >> 4) << 2);
    int cbase = col0 + (lane & 15);
#pragma unroll
    for (int mi = 0; mi < 2; ++mi) {
        int rg = rbase + mi * 16;
#pragma unroll
        for (int ni = 0; ni < 4; ++ni) {
            int col = cbase + ni * 16;
            float bias = fcb[col];
            bf16x4 tv;
#pragma unroll
            for (int r = 0; r < 4; ++r) {
                float v = acc[mi][ni][r] + bias;
                size_t idx = (size_t)(rg + r) * 256 + col;
                bf16 hi = (bf16)v;
                bf16 lo = (bf16)(v - (float)hi);
                hb[idx] = hi;
                hlo[idx] = lo;
                tv[r] = hi;
            }
            int b = rg >> 10, n = rg & 1023;
            *(bf16x4*)&hT[(((size_t)(b * 256 + col)) << 10) + n] = tv;
        }
    }
}

// ---------- fused Euler step: 256x128 tile, 512 threads, 1 block/CU ---------
template <bool LAST>
__launch_bounds__(512, 1)
__global__ void gemm_step(const bf16* __restrict__ adjb, const bf16* __restrict__ hbp,
                          const bf16* __restrict__ hTp, const bf16* __restrict__ weffT,
                          const float* __restrict__ ahs, const bf16* __restrict__ x0b,
                          bf16* __restrict__ hlo, bf16* __restrict__ hbn,
                          bf16* __restrict__ hTn, float* __restrict__ out) {
    __shared__ __align__(16) bf16 As[3][16384];
    __shared__ __align__(16) bf16 Bs[3][8192];
    int t = threadIdx.x, lane = t & 63, wv = t >> 6;
    int wm = wv >> 1, wn = wv & 1;
    // grid 256 = 32 b x (4 n-tiles x 2 d-tiles); batch keyed to XCD.
    int g = blockIdx.x;
    int xcd = g & 7, idx = g >> 3;       // idx 0..31
    int b = (idx & 3) * 8 + xcd;
    int tile = idx >> 2;                 // 0..7
    int n0 = (tile & 3) * 256;
    int d0 = (tile >> 2) * 128;
    f32x4 acc[4][4] = {};

    const bf16* A1 = adjb + (size_t)n0 * 1024;                  // K=1024, 16 tiles
    const bf16* B1 = hTp + ((size_t)(b * 256 + d0)) * 1024;
    const bf16* A2 = hbp + ((size_t)(b * 1024 + n0)) * 256;     // K=256, 4 tiles
    const bf16* B2 = weffT + (size_t)d0 * 256;
    auto tadr = [&](int i, const bf16*& Ag, int& lda, const bf16*& Bg, int& ldb) {
        if (i < 16) {
            Ag = A1 + i * 64; lda = 1024;
            Bg = B1 + i * 64; ldb = 1024;
        } else {
            Ag = A2 + (i - 16) * 64; lda = 256;
            Bg = B2 + (i - 16) * 64; ldb = 256;
        }
    };
    run_pipe2<20>(tadr, As, Bs, acc, t, lane, wm, wn);

    const float dt = 0.125f;
    int l15 = lane & 15;
    int lq = (lane >> 4) << 2;           // 0,4,8,12
#pragma unroll
    for (int mi = 0; mi < 4; ++mi) {
        int nr = n0 + wm * 64 + mi * 16 + lq;
#pragma unroll
        for (int ni = 0; ni < 4; ++ni) {
            int col = d0 + wn * 64 + ni * 16 + l15;
            bf16x4 tv;
#pragma unroll
            for (int r = 0; r < 4; ++r) {
                int node = nr + r;
                size_t idx2 = (((size_t)b << 10) + node) * 256 + col;
                float hi = (float)hbp[idx2];
                float lo = (float)hlo[idx2];
                float hold = hi + lo;
                float f = acc[mi][ni][r] - (ahs[node] + 1.0f) * hold + (float)x0b[idx2];
                float hv = hold + dt * f;
                if (LAST) {
                    out[idx2] = hv;
                } else {
                    bf16 nhi = (bf16)hv;
                    bf16 nlo = (bf16)(hv - (float)nhi);
                    hbn[idx2] = nhi;
                    hlo[idx2] = nlo;
                    tv[r] = nhi;
                }
            }
            if (!LAST)
                *(bf16x4*)&hTn[(((size_t)(b * 256 + col)) << 10) + nr] = tv;
        }
    }
}

extern "C" void kernel_launch(void* const* d_in, const int* in_sizes, int n_in,
                              void* d_out, int out_size, void* d_ws, size_t ws_size,
                              hipStream_t stream) {
    const float* x     = (const float*)d_in[0];
    const float* adj   = (const float*)d_in[1];
    const float* alpha = (const float*)d_in[2];
    const float* w     = (const float*)d_in[3];
    const float* dvec  = (const float*)d_in[4];
    const float* fcw   = (const float*)d_in[5];
    const float* fcb   = (const float*)d_in[6];
    float* out = (float*)d_out;   // fp32 h, written by the LAST step only

    const size_t HB = (size_t)32 * 1024 * 256 * 2;  // 16 MiB
    char* p = (char*)d_ws;
    bf16* hb0   = (bf16*)p; p += HB;
    bf16* hb1   = (bf16*)p; p += HB;
    bf16* hT0   = (bf16*)p; p += HB;
    bf16* hT1   = (bf16*)p; p += HB;
    bf16* xb    = (bf16*)p; p += HB;
    bf16* hlo   = (bf16*)p; p += HB;   // single in-place residual buffer
    bf16* adjb  = (bf16*)p; p += (size_t)1024 * 1024 * 2;
    bf16* fcwb  = (bf16*)p; p += 256 * 256 * 2;
    bf16* weffT = (bf16*)p; p += 256 * 256 * 2;
    float* ahs  = (float*)p; p += 1024 * 4;

    prep_alpha<<<4, 256, 0, stream>>>(alpha, ahs);
    prep_adj<<<1024, 256, 0, stream>>>(adj, ahs, adjb);
    prep_weff<<<256, 256, 0, stream>>>(w, dvec, weffT);
    cast_f32_bf16x4<<<8192, 256, 0, stream>>>(x, xb, 2097152);
    cast_f32_bf16x4<<<64, 256, 0, stream>>>(fcw, fcwb, 16384);

    gemm_fcin<<<dim3(4, 256), 256, 0, stream>>>(xb, fcwb, fcb, hb0, hT0, hlo);

    bf16* hb[2] = {hb0, hb1};
    bf16* hT[2] = {hT0, hT1};
    int cur = 0;
    for (int s = 0; s < 8; ++s) {
        if (s < 7)
            gemm_step<false><<<256, 512, 0, stream>>>(
                adjb, hb[cur], hT[cur], weffT, ahs, xb, hlo,
                hb[cur ^ 1], hT[cur ^ 1], out);
        else
            gemm_step<true><<<256, 512, 0, stream>>>(
                adjb, hb[cur], hT[cur], weffT, ahs, xb, hlo,
                hb[cur ^ 1], hT[cur ^ 1], out);
        cur ^= 1;
    }
}

// Round 7
// 404.874 us; speedup vs baseline: 1.2748x; 1.0678x over previous
//
#include <hip/hip_runtime.h>
#include <hip/hip_bf16.h>
#include <stdint.h>

typedef __bf16 bf16;
typedef __bf16 bf16x8 __attribute__((ext_vector_type(8)));
typedef __bf16 bf16x4 __attribute__((ext_vector_type(4)));
typedef float f32x4 __attribute__((ext_vector_type(4)));
typedef unsigned short u16;

__device__ __forceinline__ void gload_lds16(const bf16* g, bf16* l) {
    __builtin_amdgcn_global_load_lds(
        (const __attribute__((address_space(1))) void*)g,
        (__attribute__((address_space(3))) void*)l, 16, 0, 0);
}

// One 16B staging chunk: XOR-swizzled global source, linear LDS dest.
__device__ __forceinline__ void stChunk(const bf16* __restrict__ g, int ld,
                                        bf16* l, int c) {
    int row = c >> 3, slot = c & 7;
    gload_lds16(g + (size_t)row * ld + ((slot ^ (row & 7)) << 3), l + c * 8);
}

// 8-MFMA cluster: rows mi,mi+1 x b0..b3 (mi is a compile-time literal at call sites).
__device__ __forceinline__ void mma8(const bf16x8& a0, const bf16x8& a1,
                                     const bf16x8& b0, const bf16x8& b1,
                                     const bf16x8& b2, const bf16x8& b3,
                                     f32x4 (&acc)[4][4], int mi) {
    acc[mi][0] = __builtin_amdgcn_mfma_f32_16x16x32_bf16(a0, b0, acc[mi][0], 0, 0, 0);
    acc[mi][1] = __builtin_amdgcn_mfma_f32_16x16x32_bf16(a0, b1, acc[mi][1], 0, 0, 0);
    acc[mi][2] = __builtin_amdgcn_mfma_f32_16x16x32_bf16(a0, b2, acc[mi][2], 0, 0, 0);
    acc[mi][3] = __builtin_amdgcn_mfma_f32_16x16x32_bf16(a0, b3, acc[mi][3], 0, 0, 0);
    acc[mi+1][0] = __builtin_amdgcn_mfma_f32_16x16x32_bf16(a1, b0, acc[mi+1][0], 0, 0, 0);
    acc[mi+1][1] = __builtin_amdgcn_mfma_f32_16x16x32_bf16(a1, b1, acc[mi+1][1], 0, 0, 0);
    acc[mi+1][2] = __builtin_amdgcn_mfma_f32_16x16x32_bf16(a1, b2, acc[mi+1][2], 0, 0, 0);
    acc[mi+1][3] = __builtin_amdgcn_mfma_f32_16x16x32_bf16(a1, b3, acc[mi+1][3], 0, 0, 0);
}

#define PHASE_SYNC_PRE()                                        \
    __builtin_amdgcn_s_barrier();                               \
    asm volatile("s_waitcnt lgkmcnt(0)" ::: "memory");          \
    __builtin_amdgcn_sched_barrier(0);                          \
    __builtin_amdgcn_s_setprio(1);
#define PHASE_SYNC_POST()                                       \
    __builtin_amdgcn_s_setprio(0);                              \
    __builtin_amdgcn_s_barrier();

// ---------- prep kernels ----------
__global__ void prep_alpha(const float* __restrict__ a, float* __restrict__ out) {
    int i = blockIdx.x * blockDim.x + threadIdx.x;
    if (i < 1024) out[i] = 0.5f / (1.0f + __expf(-a[i]));
}

__global__ void prep_adj(const float* __restrict__ adj, const float* __restrict__ ahs,
                         bf16* __restrict__ adjb) {
    int i = blockIdx.x * blockDim.x + threadIdx.x;
    int row = i >> 8;
    float s = ahs[row];
    float4 v = ((const float4*)adj)[i];
    bf16x4 o = {(bf16)(s * v.x), (bf16)(s * v.y), (bf16)(s * v.z), (bf16)(s * v.w)};
    ((bf16x4*)adjb)[i] = o;
}

__global__ void cast_f32_bf16x4(const float* __restrict__ src, bf16* __restrict__ dst,
                                int n4) {
    int i = blockIdx.x * blockDim.x + threadIdx.x;
    if (i < n4) {
        float4 v = ((const float4*)src)[i];
        bf16x4 o = {(bf16)v.x, (bf16)v.y, (bf16)v.z, (bf16)v.w};
        ((bf16x4*)dst)[i] = o;
    }
}

__global__ void prep_weff(const float* __restrict__ w, const float* __restrict__ dv,
                          bf16* __restrict__ weffT) {
    __shared__ float wk[256];
    __shared__ float dd[256];
    int k = blockIdx.x, j = threadIdx.x;
    dd[j] = fminf(fmaxf(dv[j], 0.0f), 1.0f);
    wk[j] = w[k * 256 + j];
    __syncthreads();
    float s = 0.0f;
#pragma unroll 8
    for (int c = 0; c < 256; ++c) s += wk[c] * dd[c] * w[j * 256 + c];
    weffT[j * 256 + k] = (bf16)s;
}

// xT[b][d][n] = bf16(x[b][n][d]); also xb[b][n][d] = bf16(x) in the same pass.
__global__ void prep_xT(const float* __restrict__ x, bf16* __restrict__ xT,
                        bf16* __restrict__ xb) {
    __shared__ bf16 tile[64][65];
    int b = blockIdx.z, n0 = blockIdx.x * 64, d0 = blockIdx.y * 64;
    int t = threadIdx.x;
    int i = t >> 4, j4 = (t & 15) * 4;
#pragma unroll
    for (int p = 0; p < 4; ++p) {
        int n = i + p * 16;
        size_t gi = (((size_t)b << 10) + n0 + n) * 256 + d0 + j4;
        float4 v = *(const float4*)&x[gi];
        bf16x4 o = {(bf16)v.x, (bf16)v.y, (bf16)v.z, (bf16)v.w};
        *(bf16x4*)&xb[gi] = o;
        tile[n][j4 + 0] = o[0]; tile[n][j4 + 1] = o[1];
        tile[n][j4 + 2] = o[2]; tile[n][j4 + 3] = o[3];
    }
    __syncthreads();
#pragma unroll
    for (int p = 0; p < 4; ++p) {
        int c = p * 256 + t;
        int d = c >> 4, nc = c & 15;
        bf16x4 o = {tile[nc * 4 + 0][d], tile[nc * 4 + 1][d],
                    tile[nc * 4 + 2][d], tile[nc * 4 + 3][d]};
        *(bf16x4*)&xT[(((size_t)(b * 256 + d0 + d)) << 10) + n0 + nc * 4] = o;
    }
}

// ---------------- fc_in machinery (256 threads, 128x64 tile) ---------------
__device__ __forceinline__ void stageA(const bf16* __restrict__ g, int lda,
                                       bf16* l, int t) {
#pragma unroll
    for (int i = 0; i < 4; ++i) stChunk(g, lda, l, (i << 8) + t);
}
__device__ __forceinline__ void stageB(const bf16* __restrict__ g, int ldb,
                                       bf16* l, int t) {
#pragma unroll
    for (int i = 0; i < 2; ++i) stChunk(g, ldb, l, (i << 8) + t);
}

__device__ __forceinline__ void mma_tile(const bf16* A, const bf16* B,
                                         f32x4 acc[2][4], int lane, int wv) {
    const int r0 = wv * 32 + (lane & 15);
    const int kq = lane >> 4;
    bf16x8 a[2][2], b[4][2];
#pragma unroll
    for (int mi = 0; mi < 2; ++mi) {
        int rA = r0 + mi * 16;
#pragma unroll
        for (int kk = 0; kk < 2; ++kk) {
            int kc = kk * 4 + kq;
            a[mi][kk] = *(const bf16x8*)&A[rA * 64 + ((kc ^ (rA & 7)) << 3)];
        }
    }
#pragma unroll
    for (int ni = 0; ni < 4; ++ni) {
        int rB = ni * 16 + (lane & 15);
#pragma unroll
        for (int kk = 0; kk < 2; ++kk) {
            int kc = kk * 4 + kq;
            b[ni][kk] = *(const bf16x8*)&B[rB * 64 + ((kc ^ (rB & 7)) << 3)];
        }
    }
#pragma unroll
    for (int kk = 0; kk < 2; ++kk)
#pragma unroll
        for (int mi = 0; mi < 2; ++mi)
#pragma unroll
            for (int ni = 0; ni < 4; ++ni)
                acc[mi][ni] = __builtin_amdgcn_mfma_f32_16x16x32_bf16(
                    a[mi][kk], b[ni][kk], acc[mi][ni], 0, 0, 0);
}

template <int NT, typename F>
__device__ __forceinline__ void run_pipeline(F tadr, bf16 (*As)[8192],
                                             bf16 (*Bs)[4096], f32x4 acc[2][4],
                                             int t, int lane, int wv) {
    {
        const bf16 *Ag, *Bg; int lda, ldb;
        tadr(0, Ag, lda, Bg, ldb);
        stageA(Ag, lda, As[0], t);
        stageB(Bg, ldb, Bs[0], t);
        if (NT > 1) {
            tadr(1, Ag, lda, Bg, ldb);
            stageA(Ag, lda, As[1], t);
            stageB(Bg, ldb, Bs[1], t);
        }
    }
    int cur = 0, pre = 2;
#pragma unroll 1
    for (int i = 0; i < NT; ++i) {
        if (i + 2 < NT) {
            const bf16 *Ag, *Bg; int lda, ldb;
            tadr(i + 2, Ag, lda, Bg, ldb);
            stageA(Ag, lda, As[pre], t);
            stageB(Bg, ldb, Bs[pre], t);
            asm volatile("s_waitcnt vmcnt(12)" ::: "memory");
        } else if (i + 1 < NT) {
            asm volatile("s_waitcnt vmcnt(6)" ::: "memory");
        } else {
            asm volatile("s_waitcnt vmcnt(0)" ::: "memory");
        }
        __builtin_amdgcn_s_barrier();
        __builtin_amdgcn_s_setprio(1);
        mma_tile(As[cur], Bs[cur], acc, lane, wv);
        __builtin_amdgcn_s_setprio(0);
        __builtin_amdgcn_s_barrier();
        cur = (cur == 2) ? 0 : cur + 1;
        pre = (pre == 2) ? 0 : pre + 1;
    }
}

// ---------- fc_in GEMM: h0 = x @ fcw^T + b ----------
__launch_bounds__(256, 2)
__global__ void gemm_fcin(const bf16* __restrict__ xb, const bf16* __restrict__ fcwb,
                          const float* __restrict__ fcb,
                          bf16* __restrict__ hb, bf16* __restrict__ hT,
                          bf16* __restrict__ hloT) {
    __shared__ __align__(16) bf16 As[3][8192];
    __shared__ __align__(16) bf16 Bs[3][4096];
    int t = threadIdx.x, lane = t & 63, wv = t >> 6;
    int row0 = blockIdx.y * 128;   // flattened b*1024+n
    int col0 = blockIdx.x * 64;
    f32x4 acc[2][4] = {};
    const bf16* Ab = xb + (size_t)row0 * 256;
    const bf16* Bb = fcwb + (size_t)col0 * 256;
    auto tadr = [&](int i, const bf16*& Ag, int& lda, const bf16*& Bg, int& ldb) {
        Ag = Ab + i * 64; lda = 256;
        Bg = Bb + i * 64; ldb = 256;
    };
    run_pipeline<4>(tadr, As, Bs, acc, t, lane, wv);

    int rbase = row0 + wv * 32 + ((lane >> 4) << 2);
    int cbase = col0 + (lane & 15);
#pragma unroll
    for (int mi = 0; mi < 2; ++mi) {
        int rg = rbase + mi * 16;
#pragma unroll
        for (int ni = 0; ni < 4; ++ni) {
            int col = cbase + ni * 16;
            float bias = fcb[col];
            bf16x4 tv, lv;
#pragma unroll
            for (int r = 0; r < 4; ++r) {
                float v = acc[mi][ni][r] + bias;
                size_t idx = (size_t)(rg + r) * 256 + col;
                bf16 hi = (bf16)v;
                hb[idx] = hi;
                tv[r] = hi;
                lv[r] = (bf16)(v - (float)hi);
            }
            int b = rg >> 10, n = rg & 1023;
            size_t tb = (((size_t)(b * 256 + col)) << 10) + n;
            *(bf16x4*)&hT[tb] = tv;
            *(bf16x4*)&hloT[tb] = lv;
        }
    }
}

// ---------- fused Euler step: 256x128 tile, 512 thr, 4-phase/K-tile ---------
template <bool LAST>
__launch_bounds__(512, 1)
__global__ void gemm_step(const bf16* __restrict__ adjb, const bf16* __restrict__ hbp,
                          const bf16* __restrict__ hTp, const bf16* __restrict__ weffT,
                          const float* __restrict__ ahs, const bf16* __restrict__ xT,
                          bf16* __restrict__ hloT, bf16* __restrict__ hbn,
                          bf16* __restrict__ hTn, float* __restrict__ out) {
    __shared__ __align__(16) char smem[147456];
    bf16 (*As)[16384] = (bf16(*)[16384])smem;            // 3 x 32 KB
    bf16 (*Bs)[8192]  = (bf16(*)[8192])(smem + 98304);   // 3 x 16 KB
    int t = threadIdx.x, lane = t & 63, wv = t >> 6;
    int wm = wv >> 1, wn = wv & 1;
    int g = blockIdx.x;
    int xcd = g & 7, bidx = g >> 3;
    int b = (bidx & 3) * 8 + xcd;
    int tile = bidx >> 2;
    int n0 = (tile & 3) * 256;
    int d0 = (tile >> 2) * 128;
    f32x4 acc[4][4] = {};

    const bf16* A1 = adjb + (size_t)n0 * 1024;
    const bf16* B1 = hTp + ((size_t)(b * 256 + d0)) * 1024;
    const bf16* A2 = hbp + ((size_t)(b * 1024 + n0)) * 256;
    const bf16* B2 = weffT + (size_t)d0 * 256;
    auto tadr = [&](int i, const bf16*& Ag, int& la, const bf16*& Bg, int& lb) {
        if (i < 16) { Ag = A1 + i * 64; la = 1024; Bg = B1 + i * 64; lb = 1024; }
        else        { Ag = A2 + (i - 16) * 64; la = 256; Bg = B2 + (i - 16) * 64; lb = 256; }
    };
    const int NT = 20;
    {   // prologue: stage tiles 0,1
        const bf16 *Ag, *Bg; int la, lb;
        tadr(0, Ag, la, Bg, lb);
#pragma unroll
        for (int k = 0; k < 4; ++k) stChunk(Ag, la, As[0], k * 512 + t);
#pragma unroll
        for (int k = 0; k < 2; ++k) stChunk(Bg, lb, Bs[0], k * 512 + t);
        tadr(1, Ag, la, Bg, lb);
#pragma unroll
        for (int k = 0; k < 4; ++k) stChunk(Ag, la, As[1], k * 512 + t);
#pragma unroll
        for (int k = 0; k < 2; ++k) stChunk(Bg, lb, Bs[1], k * 512 + t);
    }
    asm volatile("s_waitcnt vmcnt(6)" ::: "memory");
    __builtin_amdgcn_s_barrier();

    const int l15 = lane & 15, kq = lane >> 4;
    const int rA0 = wm * 64 + l15, rB0 = wn * 64 + l15;
    int cur = 0;
#pragma unroll 1
    for (int i = 0; i < NT; ++i) {
        const bf16* A = As[cur];
        const bf16* B = Bs[cur];
        int pre = cur + 2; if (pre >= 3) pre -= 3;
        const bf16 *Ag = nullptr, *Bg = nullptr; int la = 0, lb = 0;
        const bool st = (i + 2 < NT);
        if (st) tadr(i + 2, Ag, la, Bg, lb);

        bf16x8 a0, a1, b0, b1, b2, b3;
        // ---- P0: kk=0, clusters mi0-1; stage A chunks 0,1
        {
            int kc = kq;
            b0 = *(const bf16x8*)&B[(rB0     ) * 64 + ((kc ^ ((rB0     ) & 7)) << 3)];
            b1 = *(const bf16x8*)&B[(rB0 + 16) * 64 + ((kc ^ ((rB0 + 16) & 7)) << 3)];
            b2 = *(const bf16x8*)&B[(rB0 + 32) * 64 + ((kc ^ ((rB0 + 32) & 7)) << 3)];
            b3 = *(const bf16x8*)&B[(rB0 + 48) * 64 + ((kc ^ ((rB0 + 48) & 7)) << 3)];
            a0 = *(const bf16x8*)&A[(rA0     ) * 64 + ((kc ^ ((rA0     ) & 7)) << 3)];
            a1 = *(const bf16x8*)&A[(rA0 + 16) * 64 + ((kc ^ ((rA0 + 16) & 7)) << 3)];
            if (st) { stChunk(Ag, la, As[pre], t); stChunk(Ag, la, As[pre], 512 + t); }
            PHASE_SYNC_PRE(); mma8(a0, a1, b0, b1, b2, b3, acc, 0); PHASE_SYNC_POST();
        }
        // ---- P1: kk=0, clusters mi2-3; stage A chunks 2,3
        {
            int kc = kq;
            a0 = *(const bf16x8*)&A[(rA0 + 32) * 64 + ((kc ^ ((rA0 + 32) & 7)) << 3)];
            a1 = *(const bf16x8*)&A[(rA0 + 48) * 64 + ((kc ^ ((rA0 + 48) & 7)) << 3)];
            if (st) { stChunk(Ag, la, As[pre], 1024 + t); stChunk(Ag, la, As[pre], 1536 + t); }
            PHASE_SYNC_PRE(); mma8(a0, a1, b0, b1, b2, b3, acc, 2); PHASE_SYNC_POST();
        }
        // ---- P2: kk=1, clusters mi0-1; stage B chunks 0,1
        {
            int kc = 4 + kq;
            b0 = *(const bf16x8*)&B[(rB0     ) * 64 + ((kc ^ ((rB0     ) & 7)) << 3)];
            b1 = *(const bf16x8*)&B[(rB0 + 16) * 64 + ((kc ^ ((rB0 + 16) & 7)) << 3)];
            b2 = *(const bf16x8*)&B[(rB0 + 32) * 64 + ((kc ^ ((rB0 + 32) & 7)) << 3)];
            b3 = *(const bf16x8*)&B[(rB0 + 48) * 64 + ((kc ^ ((rB0 + 48) & 7)) << 3)];
            a0 = *(const bf16x8*)&A[(rA0     ) * 64 + ((kc ^ ((rA0     ) & 7)) << 3)];
            a1 = *(const bf16x8*)&A[(rA0 + 16) * 64 + ((kc ^ ((rA0 + 16) & 7)) << 3)];
            if (st) { stChunk(Bg, lb, Bs[pre], t); stChunk(Bg, lb, Bs[pre], 512 + t); }
            PHASE_SYNC_PRE(); mma8(a0, a1, b0, b1, b2, b3, acc, 0); PHASE_SYNC_POST();
        }
        // ---- P3: kk=1, clusters mi2-3; vmcnt gate for tile i+1
        {
            int kc = 4 + kq;
            a0 = *(const bf16x8*)&A[(rA0 + 32) * 64 + ((kc ^ ((rA0 + 32) & 7)) << 3)];
            a1 = *(const bf16x8*)&A[(rA0 + 48) * 64 + ((kc ^ ((rA0 + 48) & 7)) << 3)];
            if (st) asm volatile("s_waitcnt vmcnt(6)" ::: "memory");
            else    asm volatile("s_waitcnt vmcnt(0)" ::: "memory");
            PHASE_SYNC_PRE(); mma8(a0, a1, b0, b1, b2, b3, acc, 2); PHASE_SYNC_POST();
        }
        cur = cur + 1; if (cur == 3) cur = 0;
    }

    // ---------------- epilogue (hT-layout vectorized) ----------------
    const float dt = 0.125f;
    const int lq = (lane >> 4) << 2;
    bf16* img = (bf16*)smem;            // [128 cols][PADN] overlay (66.5 KB)
    const int PADN = 260;
#pragma unroll
    for (int mi = 0; mi < 4; ++mi) {
        int nl = wm * 64 + mi * 16 + lq;         // local node base (x4 aligned)
        int ng = n0 + nl;
        f32x4 av = *(const f32x4*)&ahs[ng];
#pragma unroll
        for (int ni = 0; ni < 4; ++ni) {
            int cl = wn * 64 + ni * 16 + l15;    // local col
            int cg = d0 + cl;
            size_t tb = (((size_t)(b * 256 + cg)) << 10) + ng;
            bf16x4 hp = *(const bf16x4*)&hTp[tb];
            bf16x4 lp = *(const bf16x4*)&hloT[tb];
            bf16x4 xp = *(const bf16x4*)&xT[tb];
            bf16x4 nhi, nlo;
#pragma unroll
            for (int r = 0; r < 4; ++r) {
                float hold = (float)hp[r] + (float)lp[r];
                float f = acc[mi][ni][r] - (av[r] + 1.0f) * hold + (float)xp[r];
                float hv = hold + dt * f;
                if (LAST) {
                    out[(((size_t)b << 10) + ng + r) * 256 + cg] = hv;
                } else {
                    bf16 hi2 = (bf16)hv;
                    nhi[r] = hi2;
                    nlo[r] = (bf16)(hv - (float)hi2);
                }
            }
            if (!LAST) {
                *(bf16x4*)&hTn[tb] = nhi;
                *(bf16x4*)&hloT[tb] = nlo;
                int nsw = nl ^ (((cl >> 3) & 7) << 2);
                *(bf16x4*)&img[cl * PADN + nsw] = nhi;
            }
        }
    }
    if (!LAST) {
        asm volatile("s_waitcnt lgkmcnt(0)" ::: "memory");
        __builtin_amdgcn_s_barrier();
        const u16* imgu = (const u16*)img;
#pragma unroll
        for (int P = 0; P < 8; ++P) {
            int chunk = P * 512 + t;
            int node = chunk >> 4;       // 0..255
            int c8 = chunk & 15;
            u16 v[8];
#pragma unroll
            for (int k = 0; k < 8; ++k) {
                int col = c8 * 8 + k;
                v[k] = imgu[col * PADN + (node ^ (((col >> 3) & 7) << 2))];
            }
            uint4 pk;
            pk.x = v[0] | ((unsigned)v[1] << 16);
            pk.y = v[2] | ((unsigned)v[3] << 16);
            pk.z = v[4] | ((unsigned)v[5] << 16);
            pk.w = v[6] | ((unsigned)v[7] << 16);
            *(uint4*)&hbn[(((size_t)b << 10) + n0 + node) * 256 + d0 + c8 * 8] = pk;
        }
    }
}

extern "C" void kernel_launch(void* const* d_in, const int* in_sizes, int n_in,
                              void* d_out, int out_size, void* d_ws, size_t ws_size,
                              hipStream_t stream) {
    const float* x     = (const float*)d_in[0];
    const float* adj   = (const float*)d_in[1];
    const float* alpha = (const float*)d_in[2];
    const float* w     = (const float*)d_in[3];
    const float* dvec  = (const float*)d_in[4];
    const float* fcw   = (const float*)d_in[5];
    const float* fcb   = (const float*)d_in[6];
    float* out = (float*)d_out;   // fp32 h, written by the LAST step only

    const size_t HB = (size_t)32 * 1024 * 256 * 2;  // 16 MiB
    char* p = (char*)d_ws;
    bf16* hb0   = (bf16*)p; p += HB;
    bf16* hb1   = (bf16*)p; p += HB;
    bf16* hT0   = (bf16*)p; p += HB;
    bf16* hT1   = (bf16*)p; p += HB;
    bf16* xb    = (bf16*)p; p += HB;
    bf16* hloT  = (bf16*)p; p += HB;
    bf16* xT    = (bf16*)p; p += HB;
    bf16* adjb  = (bf16*)p; p += (size_t)1024 * 1024 * 2;
    bf16* fcwb  = (bf16*)p; p += 256 * 256 * 2;
    bf16* weffT = (bf16*)p; p += 256 * 256 * 2;
    float* ahs  = (float*)p; p += 1024 * 4;

    prep_alpha<<<4, 256, 0, stream>>>(alpha, ahs);
    prep_adj<<<1024, 256, 0, stream>>>(adj, ahs, adjb);
    prep_weff<<<256, 256, 0, stream>>>(w, dvec, weffT);
    prep_xT<<<dim3(16, 4, 32), 256, 0, stream>>>(x, xT, xb);
    cast_f32_bf16x4<<<64, 256, 0, stream>>>(fcw, fcwb, 16384);

    gemm_fcin<<<dim3(4, 256), 256, 0, stream>>>(xb, fcwb, fcb, hb0, hT0, hloT);

    bf16* hb[2] = {hb0, hb1};
    bf16* hT[2] = {hT0, hT1};
    int cur = 0;
    for (int s = 0; s < 8; ++s) {
        if (s < 7)
            gemm_step<false><<<256, 512, 0, stream>>>(
                adjb, hb[cur], hT[cur], weffT, ahs, xT, hloT,
                hb[cur ^ 1], hT[cur ^ 1], out);
        else
            gemm_step<true><<<256, 512, 0, stream>>>(
                adjb, hb[cur], hT[cur], weffT, ahs, xT, hloT,
                hb[cur ^ 1], hT[cur ^ 1], out);
        cur ^= 1;
    }
}

// Round 8
// 397.337 us; speedup vs baseline: 1.2989x; 1.0190x over previous
//
#include <hip/hip_runtime.h>
#include <hip/hip_bf16.h>
#include <stdint.h>

typedef __bf16 bf16;
typedef __bf16 bf16x8 __attribute__((ext_vector_type(8)));
typedef __bf16 bf16x4 __attribute__((ext_vector_type(4)));
typedef float f32x4 __attribute__((ext_vector_type(4)));
typedef unsigned short u16;

__device__ __forceinline__ void gload_lds16(const bf16* g, bf16* l) {
    __builtin_amdgcn_global_load_lds(
        (const __attribute__((address_space(1))) void*)g,
        (__attribute__((address_space(3))) void*)l, 16, 0, 0);
}

// One 16B staging chunk: XOR-swizzled global source, linear LDS dest.
__device__ __forceinline__ void stChunk(const bf16* __restrict__ g, int ld,
                                        bf16* l, int c) {
    int row = c >> 3, slot = c & 7;
    gload_lds16(g + (size_t)row * ld + ((slot ^ (row & 7)) << 3), l + c * 8);
}

// Swizzled LDS fragment read: row-major [rows][64] bf16, kc = 16B slot 0..7.
#define LDSW(buf, row, kc) \
    (*(const bf16x8*)&(buf)[(row) * 64 + ((((kc) ^ ((row) & 7))) << 3)])

// ---------- prep kernels ----------
__global__ void prep_alpha(const float* __restrict__ a, float* __restrict__ out) {
    int i = blockIdx.x * blockDim.x + threadIdx.x;
    if (i < 1024) out[i] = 0.5f / (1.0f + __expf(-a[i]));
}

__global__ void prep_adj(const float* __restrict__ adj, const float* __restrict__ ahs,
                         bf16* __restrict__ adjb) {
    int i = blockIdx.x * blockDim.x + threadIdx.x;
    int row = i >> 8;
    float s = ahs[row];
    float4 v = ((const float4*)adj)[i];
    bf16x4 o = {(bf16)(s * v.x), (bf16)(s * v.y), (bf16)(s * v.z), (bf16)(s * v.w)};
    ((bf16x4*)adjb)[i] = o;
}

__global__ void cast_f32_bf16x4(const float* __restrict__ src, bf16* __restrict__ dst,
                                int n4) {
    int i = blockIdx.x * blockDim.x + threadIdx.x;
    if (i < n4) {
        float4 v = ((const float4*)src)[i];
        bf16x4 o = {(bf16)v.x, (bf16)v.y, (bf16)v.z, (bf16)v.w};
        ((bf16x4*)dst)[i] = o;
    }
}

__global__ void prep_weff(const float* __restrict__ w, const float* __restrict__ dv,
                          bf16* __restrict__ weffT) {
    __shared__ float wk[256];
    __shared__ float dd[256];
    int k = blockIdx.x, j = threadIdx.x;
    dd[j] = fminf(fmaxf(dv[j], 0.0f), 1.0f);
    wk[j] = w[k * 256 + j];
    __syncthreads();
    float s = 0.0f;
#pragma unroll 8
    for (int c = 0; c < 256; ++c) s += wk[c] * dd[c] * w[j * 256 + c];
    weffT[j * 256 + k] = (bf16)s;
}

// xT[b][d][n] = bf16(x[b][n][d]); also xb[b][n][d] = bf16(x) in the same pass.
__global__ void prep_xT(const float* __restrict__ x, bf16* __restrict__ xT,
                        bf16* __restrict__ xb) {
    __shared__ bf16 tile[64][65];
    int b = blockIdx.z, n0 = blockIdx.x * 64, d0 = blockIdx.y * 64;
    int t = threadIdx.x;
    int i = t >> 4, j4 = (t & 15) * 4;
#pragma unroll
    for (int p = 0; p < 4; ++p) {
        int n = i + p * 16;
        size_t gi = (((size_t)b << 10) + n0 + n) * 256 + d0 + j4;
        float4 v = *(const float4*)&x[gi];
        bf16x4 o = {(bf16)v.x, (bf16)v.y, (bf16)v.z, (bf16)v.w};
        *(bf16x4*)&xb[gi] = o;
        tile[n][j4 + 0] = o[0]; tile[n][j4 + 1] = o[1];
        tile[n][j4 + 2] = o[2]; tile[n][j4 + 3] = o[3];
    }
    __syncthreads();
#pragma unroll
    for (int p = 0; p < 4; ++p) {
        int c = p * 256 + t;
        int d = c >> 4, nc = c & 15;
        bf16x4 o = {tile[nc * 4 + 0][d], tile[nc * 4 + 1][d],
                    tile[nc * 4 + 2][d], tile[nc * 4 + 3][d]};
        *(bf16x4*)&xT[(((size_t)(b * 256 + d0 + d)) << 10) + n0 + nc * 4] = o;
    }
}

// ---------------- fc_in machinery (256 threads, 128x64 tile) ---------------
__device__ __forceinline__ void stageA4(const bf16* __restrict__ g, int lda,
                                        bf16* l, int t) {
#pragma unroll
    for (int i = 0; i < 4; ++i) stChunk(g, lda, l, (i << 8) + t);
}
__device__ __forceinline__ void stageB2(const bf16* __restrict__ g, int ldb,
                                        bf16* l, int t) {
#pragma unroll
    for (int i = 0; i < 2; ++i) stChunk(g, ldb, l, (i << 8) + t);
}

__device__ __forceinline__ void mma_tile(const bf16* A, const bf16* B,
                                         f32x4 acc[2][4], int lane, int wv) {
    const int r0 = wv * 32 + (lane & 15);
    const int kq = lane >> 4;
    bf16x8 a[2][2], b[4][2];
#pragma unroll
    for (int mi = 0; mi < 2; ++mi) {
        int rA = r0 + mi * 16;
#pragma unroll
        for (int kk = 0; kk < 2; ++kk) a[mi][kk] = LDSW(A, rA, kk * 4 + kq);
    }
#pragma unroll
    for (int ni = 0; ni < 4; ++ni) {
        int rB = ni * 16 + (lane & 15);
#pragma unroll
        for (int kk = 0; kk < 2; ++kk) b[ni][kk] = LDSW(B, rB, kk * 4 + kq);
    }
#pragma unroll
    for (int kk = 0; kk < 2; ++kk)
#pragma unroll
        for (int mi = 0; mi < 2; ++mi)
#pragma unroll
            for (int ni = 0; ni < 4; ++ni)
                acc[mi][ni] = __builtin_amdgcn_mfma_f32_16x16x32_bf16(
                    a[mi][kk], b[ni][kk], acc[mi][ni], 0, 0, 0);
}

template <int NT, typename F>
__device__ __forceinline__ void run_pipeline(F tadr, bf16 (*As)[8192],
                                             bf16 (*Bs)[4096], f32x4 acc[2][4],
                                             int t, int lane, int wv) {
    {
        const bf16 *Ag, *Bg; int lda, ldb;
        tadr(0, Ag, lda, Bg, ldb);
        stageA4(Ag, lda, As[0], t);
        stageB2(Bg, ldb, Bs[0], t);
        if (NT > 1) {
            tadr(1, Ag, lda, Bg, ldb);
            stageA4(Ag, lda, As[1], t);
            stageB2(Bg, ldb, Bs[1], t);
        }
    }
    int cur = 0, pre = 2;
#pragma unroll 1
    for (int i = 0; i < NT; ++i) {
        if (i + 2 < NT) {
            const bf16 *Ag, *Bg; int lda, ldb;
            tadr(i + 2, Ag, lda, Bg, ldb);
            stageA4(Ag, lda, As[pre], t);
            stageB2(Bg, ldb, Bs[pre], t);
            asm volatile("s_waitcnt vmcnt(12)" ::: "memory");
        } else if (i + 1 < NT) {
            asm volatile("s_waitcnt vmcnt(6)" ::: "memory");
        } else {
            asm volatile("s_waitcnt vmcnt(0)" ::: "memory");
        }
        __builtin_amdgcn_s_barrier();
        __builtin_amdgcn_s_setprio(1);
        mma_tile(As[cur], Bs[cur], acc, lane, wv);
        __builtin_amdgcn_s_setprio(0);
        __builtin_amdgcn_s_barrier();
        cur = (cur == 2) ? 0 : cur + 1;
        pre = (pre == 2) ? 0 : pre + 1;
    }
}

// ---------- fc_in GEMM: h0 = x @ fcw^T + b ----------
__launch_bounds__(256, 2)
__global__ void gemm_fcin(const bf16* __restrict__ xb, const bf16* __restrict__ fcwb,
                          const float* __restrict__ fcb,
                          bf16* __restrict__ hb, bf16* __restrict__ hT,
                          bf16* __restrict__ hloT) {
    __shared__ __align__(16) bf16 As[3][8192];
    __shared__ __align__(16) bf16 Bs[3][4096];
    int t = threadIdx.x, lane = t & 63, wv = t >> 6;
    int row0 = blockIdx.y * 128;   // flattened b*1024+n
    int col0 = blockIdx.x * 64;
    f32x4 acc[2][4] = {};
    const bf16* Ab = xb + (size_t)row0 * 256;
    const bf16* Bb = fcwb + (size_t)col0 * 256;
    auto tadr = [&](int i, const bf16*& Ag, int& lda, const bf16*& Bg, int& ldb) {
        Ag = Ab + i * 64; lda = 256;
        Bg = Bb + i * 64; ldb = 256;
    };
    run_pipeline<4>(tadr, As, Bs, acc, t, lane, wv);

    int rbase = row0 + wv * 32 + ((lane >> 4) << 2);
    int cbase = col0 + (lane & 15);
#pragma unroll
    for (int mi = 0; mi < 2; ++mi) {
        int rg = rbase + mi * 16;
#pragma unroll
        for (int ni = 0; ni < 4; ++ni) {
            int col = cbase + ni * 16;
            float bias = fcb[col];
            bf16x4 tv, lv;
#pragma unroll
            for (int r = 0; r < 4; ++r) {
                float v = acc[mi][ni][r] + bias;
                size_t idx = (size_t)(rg + r) * 256 + col;
                bf16 hi = (bf16)v;
                hb[idx] = hi;
                tv[r] = hi;
                lv[r] = (bf16)(v - (float)hi);
            }
            int b = rg >> 10, n = rg & 1023;
            size_t tb = (((size_t)(b * 256 + col)) << 10) + n;
            *(bf16x4*)&hT[tb] = tv;
            *(bf16x4*)&hloT[tb] = lv;
        }
    }
}

// ---------- fused Euler step: 256x128 tile, 512 thr, 2-phase/K-tile ---------
template <bool LAST>
__launch_bounds__(512, 1)
__global__ void gemm_step(const bf16* __restrict__ adjb, const bf16* __restrict__ hbp,
                          const bf16* __restrict__ hTp, const bf16* __restrict__ weffT,
                          const float* __restrict__ ahs, const bf16* __restrict__ xT,
                          bf16* __restrict__ hloT, bf16* __restrict__ hbn,
                          bf16* __restrict__ hTn, float* __restrict__ out) {
    __shared__ __align__(16) char smem[147456];
    bf16 (*As)[16384] = (bf16(*)[16384])smem;            // 3 x 32 KB
    bf16 (*Bs)[8192]  = (bf16(*)[8192])(smem + 98304);   // 3 x 16 KB
    int t = threadIdx.x, lane = t & 63, wv = t >> 6;
    int wm = wv >> 1, wn = wv & 1;
    int g = blockIdx.x;
    int xcd = g & 7, bidx = g >> 3;
    int b = (bidx & 3) * 8 + xcd;
    int tile = bidx >> 2;
    int n0 = (tile & 3) * 256;
    int d0 = (tile >> 2) * 128;
    f32x4 acc[4][4] = {};

    const bf16* A1 = adjb + (size_t)n0 * 1024;
    const bf16* B1 = hTp + ((size_t)(b * 256 + d0)) * 1024;
    const bf16* A2 = hbp + ((size_t)(b * 1024 + n0)) * 256;
    const bf16* B2 = weffT + (size_t)d0 * 256;
    auto tadr = [&](int i, const bf16*& Ag, int& la, const bf16*& Bg, int& lb) {
        if (i < 16) { Ag = A1 + i * 64; la = 1024; Bg = B1 + i * 64; lb = 1024; }
        else        { Ag = A2 + (i - 16) * 64; la = 256; Bg = B2 + (i - 16) * 64; lb = 256; }
    };
    const int NT = 20;
    {   // prologue: stage tiles 0,1
        const bf16 *Ag, *Bg; int la, lb;
        tadr(0, Ag, la, Bg, lb);
#pragma unroll
        for (int k = 0; k < 4; ++k) stChunk(Ag, la, As[0], k * 512 + t);
#pragma unroll
        for (int k = 0; k < 2; ++k) stChunk(Bg, lb, Bs[0], k * 512 + t);
        tadr(1, Ag, la, Bg, lb);
#pragma unroll
        for (int k = 0; k < 4; ++k) stChunk(Ag, la, As[1], k * 512 + t);
#pragma unroll
        for (int k = 0; k < 2; ++k) stChunk(Bg, lb, Bs[1], k * 512 + t);
    }
    const int l15 = lane & 15, kq = lane >> 4;
    const int rA[4] = {wm * 64 + l15, wm * 64 + 16 + l15,
                       wm * 64 + 32 + l15, wm * 64 + 48 + l15};
    const int rB[4] = {wn * 64 + l15, wn * 64 + 16 + l15,
                       wn * 64 + 32 + l15, wn * 64 + 48 + l15};

    asm volatile("s_waitcnt vmcnt(6)" ::: "memory");
    __builtin_amdgcn_s_barrier();

    // loop-carried kk0 fragment set (pa/pb), issued one phase ahead
    bf16x8 pa[4], pb[4];
#pragma unroll
    for (int j = 0; j < 4; ++j) pb[j] = LDSW(Bs[0], rB[j], kq);
#pragma unroll
    for (int j = 0; j < 4; ++j) pa[j] = LDSW(As[0], rA[j], kq);

    int cur = 0;
#pragma unroll 1
    for (int i = 0; i < NT; ++i) {
        const bf16* Ab = As[cur];
        const bf16* Bb = Bs[cur];
        int nxt = cur + 1; if (nxt == 3) nxt = 0;
        int pre = cur + 2; if (pre >= 3) pre -= 3;
        const bool st2 = (i + 2 < NT), st1 = (i + 1 < NT);
        const bf16 *Ag = nullptr, *Bg = nullptr; int la = 0, lb = 0;
        if (st2) tadr(i + 2, Ag, la, Bg, lb);

        // ---- Pa: issue kk1 frag reads (8) + 4 A stage chunks; mma kk0 (16)
        bf16x8 qa[4], qb[4];
#pragma unroll
        for (int j = 0; j < 4; ++j) qb[j] = LDSW(Bb, rB[j], 4 + kq);
#pragma unroll
        for (int j = 0; j < 4; ++j) qa[j] = LDSW(Ab, rA[j], 4 + kq);
        if (st2) {
            stChunk(Ag, la, As[pre], t);        stChunk(Ag, la, As[pre], 512 + t);
            stChunk(Ag, la, As[pre], 1024 + t); stChunk(Ag, la, As[pre], 1536 + t);
        }
        __builtin_amdgcn_s_barrier();
        asm volatile("s_waitcnt lgkmcnt(8)" ::: "memory");
        __builtin_amdgcn_sched_barrier(0);
        __builtin_amdgcn_s_setprio(1);
#pragma unroll
        for (int mi = 0; mi < 4; ++mi)
#pragma unroll
            for (int ni = 0; ni < 4; ++ni)
                acc[mi][ni] = __builtin_amdgcn_mfma_f32_16x16x32_bf16(
                    pa[mi], pb[ni], acc[mi][ni], 0, 0, 0);
        __builtin_amdgcn_s_setprio(0);
        __builtin_amdgcn_s_barrier();

        // ---- Pb: 2 B stage chunks; vmcnt gate; issue next kk0 reads; mma kk1
        if (st2) {
            stChunk(Bg, lb, Bs[pre], t); stChunk(Bg, lb, Bs[pre], 512 + t);
            asm volatile("s_waitcnt vmcnt(6)" ::: "memory");
        } else {
            asm volatile("s_waitcnt vmcnt(0)" ::: "memory");
        }
        __builtin_amdgcn_s_barrier();
        if (st1) {
            const bf16* An = As[nxt];
            const bf16* Bn = Bs[nxt];
#pragma unroll
            for (int j = 0; j < 4; ++j) pb[j] = LDSW(Bn, rB[j], kq);
#pragma unroll
            for (int j = 0; j < 4; ++j) pa[j] = LDSW(An, rA[j], kq);
            asm volatile("s_waitcnt lgkmcnt(8)" ::: "memory");
        } else {
            asm volatile("s_waitcnt lgkmcnt(0)" ::: "memory");
        }
        __builtin_amdgcn_sched_barrier(0);
        __builtin_amdgcn_s_setprio(1);
#pragma unroll
        for (int mi = 0; mi < 4; ++mi)
#pragma unroll
            for (int ni = 0; ni < 4; ++ni)
                acc[mi][ni] = __builtin_amdgcn_mfma_f32_16x16x32_bf16(
                    qa[mi], qb[ni], acc[mi][ni], 0, 0, 0);
        __builtin_amdgcn_s_setprio(0);
        __builtin_amdgcn_s_barrier();
        cur = nxt;
    }

    // ---------------- epilogue (hT-layout vectorized) ----------------
    const float dt = 0.125f;
    const int lq = (lane >> 4) << 2;
    bf16* img = (bf16*)smem;            // [128 cols][PADN] overlay
    const int PADN = 260;
#pragma unroll
    for (int mi = 0; mi < 4; ++mi) {
        int nl = wm * 64 + mi * 16 + lq;         // local node base (x4 aligned)
        int ng = n0 + nl;
        f32x4 av = *(const f32x4*)&ahs[ng];
#pragma unroll
        for (int ni = 0; ni < 4; ++ni) {
            int cl = wn * 64 + ni * 16 + l15;    // local col
            int cg = d0 + cl;
            size_t tb = (((size_t)(b * 256 + cg)) << 10) + ng;
            bf16x4 hp = *(const bf16x4*)&hTp[tb];
            bf16x4 lp = *(const bf16x4*)&hloT[tb];
            bf16x4 xp = *(const bf16x4*)&xT[tb];
            bf16x4 nhi, nlo;
#pragma unroll
            for (int r = 0; r < 4; ++r) {
                float hold = (float)hp[r] + (float)lp[r];
                float f = acc[mi][ni][r] - (av[r] + 1.0f) * hold + (float)xp[r];
                float hv = hold + dt * f;
                if (LAST) {
                    out[(((size_t)b << 10) + ng + r) * 256 + cg] = hv;
                } else {
                    bf16 hi2 = (bf16)hv;
                    nhi[r] = hi2;
                    nlo[r] = (bf16)(hv - (float)hi2);
                }
            }
            if (!LAST) {
                *(bf16x4*)&hTn[tb] = nhi;
                *(bf16x4*)&hloT[tb] = nlo;
                int nsw = nl ^ (((cl >> 3) & 7) << 2);
                *(bf16x4*)&img[cl * PADN + nsw] = nhi;
            }
        }
    }
    if (!LAST) {
        asm volatile("s_waitcnt lgkmcnt(0)" ::: "memory");
        __builtin_amdgcn_s_barrier();
        const u16* imgu = (const u16*)img;
#pragma unroll
        for (int P = 0; P < 8; ++P) {
            int chunk = P * 512 + t;
            int node = chunk >> 4;       // 0..255
            int c8 = chunk & 15;
            u16 v[8];
#pragma unroll
            for (int k = 0; k < 8; ++k) {
                int col = c8 * 8 + k;
                v[k] = imgu[col * PADN + (node ^ (((col >> 3) & 7) << 2))];
            }
            uint4 pk;
            pk.x = v[0] | ((unsigned)v[1] << 16);
            pk.y = v[2] | ((unsigned)v[3] << 16);
            pk.z = v[4] | ((unsigned)v[5] << 16);
            pk.w = v[6] | ((unsigned)v[7] << 16);
            *(uint4*)&hbn[(((size_t)b << 10) + n0 + node) * 256 + d0 + c8 * 8] = pk;
        }
    }
}

extern "C" void kernel_launch(void* const* d_in, const int* in_sizes, int n_in,
                              void* d_out, int out_size, void* d_ws, size_t ws_size,
                              hipStream_t stream) {
    const float* x     = (const float*)d_in[0];
    const float* adj   = (const float*)d_in[1];
    const float* alpha = (const float*)d_in[2];
    const float* w     = (const float*)d_in[3];
    const float* dvec  = (const float*)d_in[4];
    const float* fcw   = (const float*)d_in[5];
    const float* fcb   = (const float*)d_in[6];
    float* out = (float*)d_out;   // fp32 h, written by the LAST step only

    const size_t HB = (size_t)32 * 1024 * 256 * 2;  // 16 MiB
    char* p = (char*)d_ws;
    bf16* hb0   = (bf16*)p; p += HB;
    bf16* hb1   = (bf16*)p; p += HB;
    bf16* hT0   = (bf16*)p; p += HB;
    bf16* hT1   = (bf16*)p; p += HB;
    bf16* xb    = (bf16*)p; p += HB;
    bf16* hloT  = (bf16*)p; p += HB;
    bf16* xT    = (bf16*)p; p += HB;
    bf16* adjb  = (bf16*)p; p += (size_t)1024 * 1024 * 2;
    bf16* fcwb  = (bf16*)p; p += 256 * 256 * 2;
    bf16* weffT = (bf16*)p; p += 256 * 256 * 2;
    float* ahs  = (float*)p; p += 1024 * 4;

    prep_alpha<<<4, 256, 0, stream>>>(alpha, ahs);
    prep_adj<<<1024, 256, 0, stream>>>(adj, ahs, adjb);
    prep_weff<<<256, 256, 0, stream>>>(w, dvec, weffT);
    prep_xT<<<dim3(16, 4, 32), 256, 0, stream>>>(x, xT, xb);
    cast_f32_bf16x4<<<64, 256, 0, stream>>>(fcw, fcwb, 16384);

    gemm_fcin<<<dim3(4, 256), 256, 0, stream>>>(xb, fcwb, fcb, hb0, hT0, hloT);

    bf16* hb[2] = {hb0, hb1};
    bf16* hT[2] = {hT0, hT1};
    int cur = 0;
    for (int s = 0; s < 8; ++s) {
        if (s < 7)
            gemm_step<false><<<256, 512, 0, stream>>>(
                adjb, hb[cur], hT[cur], weffT, ahs, xT, hloT,
                hb[cur ^ 1], hT[cur ^ 1], out);
        else
            gemm_step<true><<<256, 512, 0, stream>>>(
                adjb, hb[cur], hT[cur], weffT, ahs, xT, hloT,
                hb[cur ^ 1], hT[cur ^ 1], out);
        cur ^= 1;
    }
}

// Round 9
// 378.328 us; speedup vs baseline: 1.3642x; 1.0502x over previous
//
#include <hip/hip_runtime.h>
#include <hip/hip_bf16.h>
#include <stdint.h>

typedef __bf16 bf16;
typedef __bf16 bf16x8 __attribute__((ext_vector_type(8)));
typedef __bf16 bf16x4 __attribute__((ext_vector_type(4)));
typedef float f32x4 __attribute__((ext_vector_type(4)));
typedef unsigned short u16;

__device__ __forceinline__ void gload_lds16(const bf16* g, bf16* l) {
    __builtin_amdgcn_global_load_lds(
        (const __attribute__((address_space(1))) void*)g,
        (__attribute__((address_space(3))) void*)l, 16, 0, 0);
}

// Stage a 128x64 bf16 tile (row stride LD, compile-time) into LDS.
// XOR-swizzled global source, linear LDS dest; 4 chunks/thread (256 thr).
template <int LD>
__device__ __forceinline__ void stage(const bf16* __restrict__ g, bf16* l, int t) {
    int sw = ((t & 7) ^ ((t >> 3) & 7)) << 3;
    size_t base = (size_t)(t >> 3) * LD + sw;
#pragma unroll
    for (int k = 0; k < 4; ++k)
        gload_lds16(g + base + (size_t)(k * 32) * LD, l + t * 8 + k * 2048);
}

// Swizzled LDS fragment read: row-major [rows][64] bf16, kc = 16B slot 0..7.
#define LDSW(buf, row, kc) \
    (*(const bf16x8*)&(buf)[(row) * 64 + ((((kc) ^ ((row) & 7))) << 3)])

// ---------- prep kernels ----------
__global__ void prep_alpha(const float* __restrict__ a, float* __restrict__ out) {
    int i = blockIdx.x * blockDim.x + threadIdx.x;
    if (i < 1024) out[i] = 0.5f / (1.0f + __expf(-a[i]));
}

__global__ void prep_adj(const float* __restrict__ adj, const float* __restrict__ ahs,
                         bf16* __restrict__ adjb) {
    int i = blockIdx.x * blockDim.x + threadIdx.x;
    int row = i >> 8;
    float s = ahs[row];
    float4 v = ((const float4*)adj)[i];
    bf16x4 o = {(bf16)(s * v.x), (bf16)(s * v.y), (bf16)(s * v.z), (bf16)(s * v.w)};
    ((bf16x4*)adjb)[i] = o;
}

__global__ void cast_f32_bf16x4(const float* __restrict__ src, bf16* __restrict__ dst,
                                int n4) {
    int i = blockIdx.x * blockDim.x + threadIdx.x;
    if (i < n4) {
        float4 v = ((const float4*)src)[i];
        bf16x4 o = {(bf16)v.x, (bf16)v.y, (bf16)v.z, (bf16)v.w};
        ((bf16x4*)dst)[i] = o;
    }
}

__global__ void prep_weff(const float* __restrict__ w, const float* __restrict__ dv,
                          bf16* __restrict__ weffT) {
    __shared__ float wk[256];
    __shared__ float dd[256];
    int k = blockIdx.x, j = threadIdx.x;
    dd[j] = fminf(fmaxf(dv[j], 0.0f), 1.0f);
    wk[j] = w[k * 256 + j];
    __syncthreads();
    float s = 0.0f;
#pragma unroll 8
    for (int c = 0; c < 256; ++c) s += wk[c] * dd[c] * w[j * 256 + c];
    weffT[j * 256 + k] = (bf16)s;
}

// xT[b][d][n] = bf16(x[b][n][d]); also xb[b][n][d] = bf16(x) in the same pass.
__global__ void prep_xT(const float* __restrict__ x, bf16* __restrict__ xT,
                        bf16* __restrict__ xb) {
    __shared__ bf16 tile[64][65];
    int b = blockIdx.z, n0 = blockIdx.x * 64, d0 = blockIdx.y * 64;
    int t = threadIdx.x;
    int i = t >> 4, j4 = (t & 15) * 4;
#pragma unroll
    for (int p = 0; p < 4; ++p) {
        int n = i + p * 16;
        size_t gi = (((size_t)b << 10) + n0 + n) * 256 + d0 + j4;
        float4 v = *(const float4*)&x[gi];
        bf16x4 o = {(bf16)v.x, (bf16)v.y, (bf16)v.z, (bf16)v.w};
        *(bf16x4*)&xb[gi] = o;
        tile[n][j4 + 0] = o[0]; tile[n][j4 + 1] = o[1];
        tile[n][j4 + 2] = o[2]; tile[n][j4 + 3] = o[3];
    }
    __syncthreads();
#pragma unroll
    for (int p = 0; p < 4; ++p) {
        int c = p * 256 + t;
        int d = c >> 4, nc = c & 15;
        bf16x4 o = {tile[nc * 4 + 0][d], tile[nc * 4 + 1][d],
                    tile[nc * 4 + 2][d], tile[nc * 4 + 3][d]};
        *(bf16x4*)&xT[(((size_t)(b * 256 + d0 + d)) << 10) + n0 + nc * 4] = o;
    }
}

// ---------------- fc_in machinery (256 threads, 128x64 tile) ---------------
__device__ __forceinline__ void stChunk(const bf16* __restrict__ g, int ld,
                                        bf16* l, int c) {
    int row = c >> 3, slot = c & 7;
    gload_lds16(g + (size_t)row * ld + ((slot ^ (row & 7)) << 3), l + c * 8);
}
__device__ __forceinline__ void stageA4(const bf16* __restrict__ g, int lda,
                                        bf16* l, int t) {
#pragma unroll
    for (int i = 0; i < 4; ++i) stChunk(g, lda, l, (i << 8) + t);
}
__device__ __forceinline__ void stageB2(const bf16* __restrict__ g, int ldb,
                                        bf16* l, int t) {
#pragma unroll
    for (int i = 0; i < 2; ++i) stChunk(g, ldb, l, (i << 8) + t);
}

__device__ __forceinline__ void mma_tile(const bf16* A, const bf16* B,
                                         f32x4 acc[2][4], int lane, int wv) {
    const int r0 = wv * 32 + (lane & 15);
    const int kq = lane >> 4;
    bf16x8 a[2][2], b[4][2];
#pragma unroll
    for (int mi = 0; mi < 2; ++mi) {
        int rA = r0 + mi * 16;
#pragma unroll
        for (int kk = 0; kk < 2; ++kk) a[mi][kk] = LDSW(A, rA, kk * 4 + kq);
    }
#pragma unroll
    for (int ni = 0; ni < 4; ++ni) {
        int rB = ni * 16 + (lane & 15);
#pragma unroll
        for (int kk = 0; kk < 2; ++kk) b[ni][kk] = LDSW(B, rB, kk * 4 + kq);
    }
#pragma unroll
    for (int kk = 0; kk < 2; ++kk)
#pragma unroll
        for (int mi = 0; mi < 2; ++mi)
#pragma unroll
            for (int ni = 0; ni < 4; ++ni)
                acc[mi][ni] = __builtin_amdgcn_mfma_f32_16x16x32_bf16(
                    a[mi][kk], b[ni][kk], acc[mi][ni], 0, 0, 0);
}

template <int NT, typename F>
__device__ __forceinline__ void run_pipeline(F tadr, bf16 (*As)[8192],
                                             bf16 (*Bs)[4096], f32x4 acc[2][4],
                                             int t, int lane, int wv) {
    {
        const bf16 *Ag, *Bg; int lda, ldb;
        tadr(0, Ag, lda, Bg, ldb);
        stageA4(Ag, lda, As[0], t);
        stageB2(Bg, ldb, Bs[0], t);
        if (NT > 1) {
            tadr(1, Ag, lda, Bg, ldb);
            stageA4(Ag, lda, As[1], t);
            stageB2(Bg, ldb, Bs[1], t);
        }
    }
    int cur = 0, pre = 2;
#pragma unroll 1
    for (int i = 0; i < NT; ++i) {
        if (i + 2 < NT) {
            const bf16 *Ag, *Bg; int lda, ldb;
            tadr(i + 2, Ag, lda, Bg, ldb);
            stageA4(Ag, lda, As[pre], t);
            stageB2(Bg, ldb, Bs[pre], t);
            asm volatile("s_waitcnt vmcnt(12)" ::: "memory");
        } else if (i + 1 < NT) {
            asm volatile("s_waitcnt vmcnt(6)" ::: "memory");
        } else {
            asm volatile("s_waitcnt vmcnt(0)" ::: "memory");
        }
        __builtin_amdgcn_s_barrier();
        mma_tile(As[cur], Bs[cur], acc, lane, wv);
        __builtin_amdgcn_s_barrier();
        cur = (cur == 2) ? 0 : cur + 1;
        pre = (pre == 2) ? 0 : pre + 1;
    }
}

// ---------- fc_in GEMM: h0 = x @ fcw^T + b ----------
__launch_bounds__(256, 2)
__global__ void gemm_fcin(const bf16* __restrict__ xb, const bf16* __restrict__ fcwb,
                          const float* __restrict__ fcb,
                          bf16* __restrict__ hb, bf16* __restrict__ hT,
                          bf16* __restrict__ hloT) {
    __shared__ __align__(16) bf16 As[3][8192];
    __shared__ __align__(16) bf16 Bs[3][4096];
    int t = threadIdx.x, lane = t & 63, wv = t >> 6;
    int row0 = blockIdx.y * 128;   // flattened b*1024+n
    int col0 = blockIdx.x * 64;
    f32x4 acc[2][4] = {};
    const bf16* Ab = xb + (size_t)row0 * 256;
    const bf16* Bb = fcwb + (size_t)col0 * 256;
    auto tadr = [&](int i, const bf16*& Ag, int& lda, const bf16*& Bg, int& ldb) {
        Ag = Ab + i * 64; lda = 256;
        Bg = Bb + i * 64; ldb = 256;
    };
    run_pipeline<4>(tadr, As, Bs, acc, t, lane, wv);

    int rbase = row0 + wv * 32 + ((lane >> 4) << 2);
    int cbase = col0 + (lane & 15);
#pragma unroll
    for (int mi = 0; mi < 2; ++mi) {
        int rg = rbase + mi * 16;
#pragma unroll
        for (int ni = 0; ni < 4; ++ni) {
            int col = cbase + ni * 16;
            float bias = fcb[col];
            bf16x4 tv, lv;
#pragma unroll
            for (int r = 0; r < 4; ++r) {
                float v = acc[mi][ni][r] + bias;
                size_t idx = (size_t)(rg + r) * 256 + col;
                bf16 hi = (bf16)v;
                hb[idx] = hi;
                tv[r] = hi;
                lv[r] = (bf16)(v - (float)hi);
            }
            int b = rg >> 10, n = rg & 1023;
            size_t tb = (((size_t)(b * 256 + col)) << 10) + n;
            *(bf16x4*)&hT[tb] = tv;
            *(bf16x4*)&hloT[tb] = lv;
        }
    }
}

// ---------- fused Euler step: 128x128 tile, 256 thr, 2 blocks/CU ----------
template <bool LAST>
__launch_bounds__(256, 2)
__global__ void gemm_step(const bf16* __restrict__ adjb, const bf16* __restrict__ hbp,
                          const bf16* __restrict__ hTp, const bf16* __restrict__ weffT,
                          const float* __restrict__ ahs, const bf16* __restrict__ xT,
                          bf16* __restrict__ hloT, bf16* __restrict__ hbn,
                          bf16* __restrict__ hTn, float* __restrict__ out) {
    __shared__ __align__(16) char smem[65536];
    bf16 (*As)[8192] = (bf16(*)[8192])smem;              // 2 x 16 KB
    bf16 (*Bs)[8192] = (bf16(*)[8192])(smem + 32768);    // 2 x 16 KB
    int t = threadIdx.x, lane = t & 63, wv = t >> 6;
    int wm = wv >> 1, wn = wv & 1;
    // grid 512 = 32 b x (8 n-tiles x 2 d-tiles); batch keyed to XCD.
    int g = blockIdx.x;
    int xcd = g & 7, rest = g >> 3;          // rest 0..63
    int b = (rest & 3) * 8 + xcd;
    int tile = rest >> 2;                    // 0..15
    int n0 = (tile & 7) * 128;
    int d0 = (tile >> 3) * 128;
    f32x4 acc[4][4] = {};

    const bf16* A1 = adjb + (size_t)n0 * 1024;                // K=1024, 16 tiles
    const bf16* B1 = hTp + ((size_t)(b * 256 + d0)) * 1024;
    const bf16* A2 = hbp + ((size_t)(b * 1024 + n0)) * 256;   // K=256, 4 tiles
    const bf16* B2 = weffT + (size_t)d0 * 256;

    const int l15 = lane & 15, kq = lane >> 4;
    int rA[4], rB[4];
#pragma unroll
    for (int j = 0; j < 4; ++j) {
        rA[j] = wm * 64 + j * 16 + l15;
        rB[j] = wn * 64 + j * 16 + l15;
    }

    // prologue: stage tile 0
    stage<1024>(A1, As[0], t);
    stage<1024>(B1, Bs[0], t);

#pragma unroll 1
    for (int i = 0; i < 20; ++i) {
        if (i + 1 < 20) {
            if (i + 1 < 16) {
                stage<1024>(A1 + (i + 1) * 64, As[(i + 1) & 1], t);
                stage<1024>(B1 + (i + 1) * 64, Bs[(i + 1) & 1], t);
            } else {
                stage<256>(A2 + (i - 15) * 64, As[(i + 1) & 1], t);
                stage<256>(B2 + (i - 15) * 64, Bs[(i + 1) & 1], t);
            }
            asm volatile("s_waitcnt vmcnt(8)" ::: "memory");  // tile i landed
        } else {
            asm volatile("s_waitcnt vmcnt(0)" ::: "memory");
        }
        __builtin_amdgcn_s_barrier();            // buf[i&1] published
        const bf16* A = As[i & 1];
        const bf16* B = Bs[i & 1];
#pragma unroll
        for (int kk = 0; kk < 2; ++kk) {
            int kc = kk * 4 + kq;
            bf16x8 a[4], bfr[4];
#pragma unroll
            for (int j = 0; j < 4; ++j) bfr[j] = LDSW(B, rB[j], kc);
#pragma unroll
            for (int j = 0; j < 4; ++j) a[j] = LDSW(A, rA[j], kc);
#pragma unroll
            for (int mi = 0; mi < 4; ++mi)
#pragma unroll
                for (int ni = 0; ni < 4; ++ni)
                    acc[mi][ni] = __builtin_amdgcn_mfma_f32_16x16x32_bf16(
                        a[mi], bfr[ni], acc[mi][ni], 0, 0, 0);
        }
        __builtin_amdgcn_s_barrier();            // reads of buf[i&1] closed
    }

    // ---------------- epilogue (hT-layout vectorized) ----------------
    const float dt = 0.125f;
    const int lq = (lane >> 4) << 2;
    bf16* img = (bf16*)smem;            // [128 cols][PADN nodes] overlay (33.8 KB)
    const int PADN = 132;
#pragma unroll
    for (int mi = 0; mi < 4; ++mi) {
        int nl = wm * 64 + mi * 16 + lq;         // local node base (x4 aligned)
        int ng = n0 + nl;
        f32x4 av = *(const f32x4*)&ahs[ng];
#pragma unroll
        for (int ni = 0; ni < 4; ++ni) {
            int cl = wn * 64 + ni * 16 + l15;    // local col
            int cg = d0 + cl;
            size_t tb = (((size_t)(b * 256 + cg)) << 10) + ng;
            bf16x4 hp = *(const bf16x4*)&hTp[tb];
            bf16x4 lp = *(const bf16x4*)&hloT[tb];
            bf16x4 xp = *(const bf16x4*)&xT[tb];
            bf16x4 nhi, nlo;
#pragma unroll
            for (int r = 0; r < 4; ++r) {
                float hold = (float)hp[r] + (float)lp[r];
                float f = acc[mi][ni][r] - (av[r] + 1.0f) * hold + (float)xp[r];
                float hv = hold + dt * f;
                if (LAST) {
                    out[(((size_t)b << 10) + ng + r) * 256 + cg] = hv;
                } else {
                    bf16 hi2 = (bf16)hv;
                    nhi[r] = hi2;
                    nlo[r] = (bf16)(hv - (float)hi2);
                }
            }
            if (!LAST) {
                *(bf16x4*)&hTn[tb] = nhi;
                *(bf16x4*)&hloT[tb] = nlo;
                int nsw = nl ^ (((cl >> 3) & 7) << 2);
                *(bf16x4*)&img[cl * PADN + nsw] = nhi;
            }
        }
    }
    if (!LAST) {
        asm volatile("s_waitcnt lgkmcnt(0)" ::: "memory");
        __builtin_amdgcn_s_barrier();
        const u16* imgu = (const u16*)img;
#pragma unroll
        for (int P = 0; P < 8; ++P) {
            int chunk = P * 256 + t;
            int node = chunk >> 4;       // 0..127
            int c8 = chunk & 15;
            u16 v[8];
#pragma unroll
            for (int k = 0; k < 8; ++k) {
                int col = c8 * 8 + k;
                v[k] = imgu[col * PADN + (node ^ (((col >> 3) & 7) << 2))];
            }
            uint4 pk;
            pk.x = v[0] | ((unsigned)v[1] << 16);
            pk.y = v[2] | ((unsigned)v[3] << 16);
            pk.z = v[4] | ((unsigned)v[5] << 16);
            pk.w = v[6] | ((unsigned)v[7] << 16);
            *(uint4*)&hbn[(((size_t)b << 10) + n0 + node) * 256 + d0 + c8 * 8] = pk;
        }
    }
}

extern "C" void kernel_launch(void* const* d_in, const int* in_sizes, int n_in,
                              void* d_out, int out_size, void* d_ws, size_t ws_size,
                              hipStream_t stream) {
    const float* x     = (const float*)d_in[0];
    const float* adj   = (const float*)d_in[1];
    const float* alpha = (const float*)d_in[2];
    const float* w     = (const float*)d_in[3];
    const float* dvec  = (const float*)d_in[4];
    const float* fcw   = (const float*)d_in[5];
    const float* fcb   = (const float*)d_in[6];
    float* out = (float*)d_out;   // fp32 h, written by the LAST step only

    const size_t HB = (size_t)32 * 1024 * 256 * 2;  // 16 MiB
    char* p = (char*)d_ws;
    bf16* hb0   = (bf16*)p; p += HB;
    bf16* hb1   = (bf16*)p; p += HB;
    bf16* hT0   = (bf16*)p; p += HB;
    bf16* hT1   = (bf16*)p; p += HB;
    bf16* xb    = (bf16*)p; p += HB;
    bf16* hloT  = (bf16*)p; p += HB;
    bf16* xT    = (bf16*)p; p += HB;
    bf16* adjb  = (bf16*)p; p += (size_t)1024 * 1024 * 2;
    bf16* fcwb  = (bf16*)p; p += 256 * 256 * 2;
    bf16* weffT = (bf16*)p; p += 256 * 256 * 2;
    float* ahs  = (float*)p; p += 1024 * 4;

    prep_alpha<<<4, 256, 0, stream>>>(alpha, ahs);
    prep_adj<<<1024, 256, 0, stream>>>(adj, ahs, adjb);
    prep_weff<<<256, 256, 0, stream>>>(w, dvec, weffT);
    prep_xT<<<dim3(16, 4, 32), 256, 0, stream>>>(x, xT, xb);
    cast_f32_bf16x4<<<64, 256, 0, stream>>>(fcw, fcwb, 16384);

    gemm_fcin<<<dim3(4, 256), 256, 0, stream>>>(xb, fcwb, fcb, hb0, hT0, hloT);

    bf16* hb[2] = {hb0, hb1};
    bf16* hT[2] = {hT0, hT1};
    int cur = 0;
    for (int s = 0; s < 8; ++s) {
        if (s < 7)
            gemm_step<false><<<512, 256, 0, stream>>>(
                adjb, hb[cur], hT[cur], weffT, ahs, xT, hloT,
                hb[cur ^ 1], hT[cur ^ 1], out);
        else
            gemm_step<true><<<512, 256, 0, stream>>>(
                adjb, hb[cur], hT[cur], weffT, ahs, xT, hloT,
                hb[cur ^ 1], hT[cur ^ 1], out);
        cur ^= 1;
    }
}